// Round 1
// baseline (808.745 us; speedup 1.0000x reference)
//
#include <hip/hip_runtime.h>
#include <math.h>

#define VV  5
#define BB  32
#define NPP 20
#define NJJ 17
#define NBB 16
#define NDD 128
#define HID 1024

static constexpr int BONE_A[NBB] = {0,0,1,2,5,5,7,6,8,5,6,11,11,13,12,14};
static constexpr int BONE_B[NBB] = {1,2,3,4,6,7,9,8,10,11,12,12,13,15,14,16};

__device__ __forceinline__ float warp_red_sum(float v) {
#pragma unroll
  for (int off = 32; off >= 1; off >>= 1) v += __shfl_xor(v, off, 64);
  return v;
}

__global__ __launch_bounds__(256) void pose_fused_kernel(
    const float* __restrict__ kpts, const float* __restrict__ joint_vis,
    const float* __restrict__ cam_R, const float* __restrict__ cam_T,
    const float* __restrict__ cam_f, const float* __restrict__ cam_c,
    const float* __restrict__ image_wh, const int* __restrict__ num_persons,
    const float* __restrict__ Wr1, const float* __restrict__ br1,
    const float* __restrict__ Wr2, const float* __restrict__ br2,
    const float* __restrict__ Wc1, const float* __restrict__ bc1,
    const float* __restrict__ Wc2, const float* __restrict__ bc2,
    float* __restrict__ out) {
  const int n = blockIdx.x;
  const int b = n / NPP;
  const int p = n % NPP;
  const int tid = threadIdx.x;

  __shared__ float sh_x[NJJ * 2];
  __shared__ float sh_h[HID];
  __shared__ float sh_rough[NJJ];
  __shared__ float sh_base[NJJ][3];
  __shared__ float sh_pr[NPP * NJJ * 2];
  __shared__ float sh_vr[NPP * NJJ];
  __shared__ float sh_xin[NJJ + NBB][NDD + 2];   // zero-padded t-axis
  __shared__ float sh_acc[3][2][NDD];            // [M,C,P][half][t]
  __shared__ float sh_l[NDD];
  __shared__ float sh_e[NDD];
  __shared__ float sh_sc[2];

  // ---------- Phase 1a: normalized view-0 keypoints (rough-MLP input) ----------
  if (tid < NJJ * 2) {
    int j = tid >> 1, c = tid & 1;
    float k = kpts[((size_t)(b * NPP + p)) * NJJ * 2 + j * 2 + c];  // view 0
    sh_x[tid] = k / image_wh[c];  // image_wh[0,0,:]
  }
  __syncthreads();

  // ---------- Phase 1b: h = relu(x @ Wr1.T + br1), 4 rows/thread ----------
#pragma unroll
  for (int k = 0; k < 4; ++k) {
    int m = tid + k * 256;
    float acc = br1[m];
#pragma unroll
    for (int c = 0; c < NJJ * 2; ++c) acc = fmaf(Wr1[m * (NJJ * 2) + c], sh_x[c], acc);
    sh_h[m] = fmaxf(acc, 0.0f);
  }
  __syncthreads();

  // ---------- Phase 1c (wave 0): rough = (h @ Wr2.T + br2)*1000 ----------
  // ---------- Phase 2  (wave 1): base_i = R0^T · (uvn_x, uvn_y, 1) ----------
  if (tid < 64) {
    for (int j = 0; j < NJJ; ++j) {
      float part = 0.0f;
      for (int m = tid; m < HID; m += 64) part = fmaf(Wr2[j * HID + m], sh_h[m], part);
      part = warp_red_sum(part);
      if (tid == 0) sh_rough[j] = (part + br2[j]) * 1000.0f;
    }
  } else if (tid < 64 + NJJ) {
    int j = tid - 64;
    const float* R0 = cam_R + (size_t)b * 9;  // view 0, batch b
    float c0x = cam_c[b * 2 + 0], c0y = cam_c[b * 2 + 1];
    float f0x = cam_f[b * 2 + 0], f0y = cam_f[b * 2 + 1];
    float kx = kpts[((size_t)(b * NPP + p)) * NJJ * 2 + j * 2 + 0];
    float ky = kpts[((size_t)(b * NPP + p)) * NJJ * 2 + j * 2 + 1];
    float ux = (kx - c0x) / f0x;
    float uy = (ky - c0y) / f0y;
#pragma unroll
    for (int i = 0; i < 3; ++i)
      sh_base[j][i] = R0[0 * 3 + i] * ux + R0[1 * 3 + i] * uy + R0[2 * 3 + i];
  }
  __syncthreads();

  // ---------- Phase 3: per-view projection, matching, scoring ----------
  float px[NJJ], py[NJJ];
  float sj[NJJ], bj[NJJ];  // scores / boundings per joint
  float s2[NBB];           // bone scores
  float b2 = 0.0f;         // boundings2 (same for all bones: joint-0 vis)
#pragma unroll
  for (int j = 0; j < NJJ; ++j) { sj[j] = 0.0f; bj[j] = 0.0f; }
#pragma unroll
  for (int nb = 0; nb < NBB; ++nb) s2[nb] = 0.0f;

  const float T0x = cam_T[b * 3 + 0], T0y = cam_T[b * 3 + 1], T0z = cam_T[b * 3 + 2];
  const float lab = ((float)(tid & (NDD - 1)) / 127.0f) * 6000.0f + 2000.0f;

  for (int rv = 1; rv < VV; ++rv) {
    __syncthreads();  // protect sh_pr/sh_vr reuse across views
    {
      const float* prg = kpts + ((size_t)rv * BB + b) * NPP * NJJ * 2;
      for (int idx = tid; idx < NPP * NJJ * 2; idx += 256) sh_pr[idx] = prg[idx];
      const float* vrg = joint_vis + ((size_t)rv * BB + b) * NPP * NJJ;
      for (int idx = tid; idx < NPP * NJJ; idx += 256) sh_vr[idx] = vrg[idx];
    }
    __syncthreads();

    if (tid < NDD) {
      const int vb = rv * BB + b;
      const float* Rr = cam_R + (size_t)vb * 9;
      const float R00 = Rr[0], R01 = Rr[1], R02 = Rr[2];
      const float R10 = Rr[3], R11 = Rr[4], R12 = Rr[5];
      const float R20 = Rr[6], R21 = Rr[7], R22 = Rr[8];
      const float Trx = cam_T[vb * 3 + 0], Try = cam_T[vb * 3 + 1], Trz = cam_T[vb * 3 + 2];
      const float frx = cam_f[vb * 2 + 0], fry = cam_f[vb * 2 + 1];
      const float crx = cam_c[vb * 2 + 0], cry = cam_c[vb * 2 + 1];
      const float wmax = image_wh[vb * 2 + 0] - 1.0f;
      const float hmax = image_wh[vb * 2 + 1] - 1.0f;
      const int nprv = num_persons[vb];

      // project all joints of this hypothesis (person p, depth d=tid)
#pragma unroll
      for (int j = 0; j < NJJ; ++j) {
        float dep = lab + sh_rough[j];
        float p0 = fmaf(dep, sh_base[j][0], T0x);
        float p1 = fmaf(dep, sh_base[j][1], T0y);
        float p2 = fmaf(dep, sh_base[j][2], T0z);
        float q0 = p0 - Trx, q1 = p1 - Try, q2 = p2 - Trz;
        float xc0 = R00 * q0 + R01 * q1 + R02 * q2;
        float xc1 = R10 * q0 + R11 * q1 + R12 * q2;
        float xc2 = R20 * q0 + R21 * q1 + R22 * q2 + 1e-8f;
        px[j] = xc0 / xc2 * frx + crx;
        py[j] = xc1 / xc2 * fry + cry;
      }

      // argmin over candidate persons q (first-min semantics)
      float best = 3.4e38f;
      int mm = 0;
      for (int q = 0; q < NPP; ++q) {
        float num = 0.0f, den = 0.0f;
#pragma unroll
        for (int j = 0; j < NJJ; ++j) {
          float w = sh_vr[q * NJJ + j];
          float dx = px[j] - sh_pr[(q * NJJ + j) * 2 + 0];
          float dy = py[j] - sh_pr[(q * NJJ + j) * 2 + 1];
          num = fmaf(w, dx * dx + dy * dy, num);
          den += w;
        }
        float pd = num / (den + 1e-8f);
        if (q >= nprv) pd = 100000.0f;
        if (pd < best) { best = pd; mm = q; }
      }

      // joint scores
#pragma unroll
      for (int j = 0; j < NJJ; ++j) {
        float mx = sh_pr[(mm * NJJ + j) * 2 + 0];
        float my = sh_pr[(mm * NJJ + j) * 2 + 1];
        float mv = sh_vr[mm * NJJ + j];
        float dx = px[j] - mx, dy = py[j] - my;
        float sc = expf(-sqrtf(dx * dx + dy * dy + 1e-12f) / 100.0f);
        float inb = (px[j] >= 0.0f && py[j] >= 0.0f && px[j] <= wmax && py[j] <= hmax) ? 1.0f : 0.0f;
        float bd = inb * mv;
        sj[j] = fmaf(sc, bd, sj[j]);
        bj[j] += bd;
      }
      // bone scores (bounding2 = matched joint-0 visibility, same for all bones)
      float v0 = sh_vr[mm * NJJ + 0];
#pragma unroll
      for (int nb = 0; nb < NBB; ++nb) {
        const int a = BONE_A[nb], c = BONE_B[nb];
        float ax = sh_pr[(mm * NJJ + a) * 2 + 0], ay = sh_pr[(mm * NJJ + a) * 2 + 1];
        float cx = sh_pr[(mm * NJJ + c) * 2 + 0], cy = sh_pr[(mm * NJJ + c) * 2 + 1];
        float dmx = ax - cx, dmy = ay - cy;
        float blm = sqrtf(dmx * dmx + dmy * dmy + 1e-12f);
        float dpx = px[a] - px[c], dpy = py[a] - py[c];
        float blp = sqrtf(dpx * dpx + dpy * dpy + 1e-12f);
        float scb = expf(-fabsf(blm - blp) / 5.0f);
        s2[nb] = fmaf(scb, v0, s2[nb]);
      }
      b2 += v0;
    }
  }

  // ---------- Phase 4: xin = [psv; psv2] into LDS (zero-padded t-axis) ----------
  if (tid < NDD) {
    int dcol = tid + 1;
#pragma unroll
    for (int j = 0; j < NJJ; ++j) sh_xin[j][dcol] = sj[j] / (bj[j] + 1e-8f);
    float den2 = b2 + 1e-8f;
#pragma unroll
    for (int nb = 0; nb < NBB; ++nb) sh_xin[NJJ + nb][dcol] = s2[nb] / den2;
  }
  if (tid < NJJ + NBB) { sh_xin[tid][0] = 0.0f; sh_xin[tid][NDD + 1] = 0.0f; }
  __syncthreads();

  // ---------- Phase 5: fused conv1(relu) + conv2 scatter ----------
  {
    const int tloc = tid & (NDD - 1);
    const int half = __builtin_amdgcn_readfirstlane(tid) >> 7;  // wave-uniform -> scalar loads
    float accM = 0.0f, accC = 0.0f, accP = 0.0f;
    const int obeg = half * (HID / 2);
    const int oend = obeg + (HID / 2);
    for (int o = obeg; o < oend; o += 4) {
      float h0 = bc1[o + 0], h1 = bc1[o + 1], h2 = bc1[o + 2], h3 = bc1[o + 3];
      const float* w0 = Wc1 + (size_t)(o + 0) * 99;
      const float* w1 = Wc1 + (size_t)(o + 1) * 99;
      const float* w2 = Wc1 + (size_t)(o + 2) * 99;
      const float* w3 = Wc1 + (size_t)(o + 3) * 99;
#pragma unroll
      for (int i = 0; i < 33; ++i) {
        float x0 = sh_xin[i][tloc + 0];
        float x1 = sh_xin[i][tloc + 1];
        float x2 = sh_xin[i][tloc + 2];
        h0 = fmaf(w0[3 * i + 0], x0, h0); h0 = fmaf(w0[3 * i + 1], x1, h0); h0 = fmaf(w0[3 * i + 2], x2, h0);
        h1 = fmaf(w1[3 * i + 0], x0, h1); h1 = fmaf(w1[3 * i + 1], x1, h1); h1 = fmaf(w1[3 * i + 2], x2, h1);
        h2 = fmaf(w2[3 * i + 0], x0, h2); h2 = fmaf(w2[3 * i + 1], x1, h2); h2 = fmaf(w2[3 * i + 2], x2, h2);
        h3 = fmaf(w3[3 * i + 0], x0, h3); h3 = fmaf(w3[3 * i + 1], x1, h3); h3 = fmaf(w3[3 * i + 2], x2, h3);
      }
      h0 = fmaxf(h0, 0.0f); h1 = fmaxf(h1, 0.0f); h2 = fmaxf(h2, 0.0f); h3 = fmaxf(h3, 0.0f);
      // hc[o,t] contributes: logits[t+1]*W[o,0] (P), logits[t]*W[o,1] (C), logits[t-1]*W[o,2] (M)
      accP = fmaf(h0, Wc2[(o + 0) * 3 + 0], accP); accP = fmaf(h1, Wc2[(o + 1) * 3 + 0], accP);
      accP = fmaf(h2, Wc2[(o + 2) * 3 + 0], accP); accP = fmaf(h3, Wc2[(o + 3) * 3 + 0], accP);
      accC = fmaf(h0, Wc2[(o + 0) * 3 + 1], accC); accC = fmaf(h1, Wc2[(o + 1) * 3 + 1], accC);
      accC = fmaf(h2, Wc2[(o + 2) * 3 + 1], accC); accC = fmaf(h3, Wc2[(o + 3) * 3 + 1], accC);
      accM = fmaf(h0, Wc2[(o + 0) * 3 + 2], accM); accM = fmaf(h1, Wc2[(o + 1) * 3 + 2], accM);
      accM = fmaf(h2, Wc2[(o + 2) * 3 + 2], accM); accM = fmaf(h3, Wc2[(o + 3) * 3 + 2], accM);
    }
    sh_acc[0][half][tloc] = accM;
    sh_acc[1][half][tloc] = accC;
    sh_acc[2][half][tloc] = accP;
  }
  __syncthreads();

  // ---------- Phase 6: logits, softmax, windowed argmax readout ----------
  if (tid < NDD) {
    int t = tid;
    float lg = bc2[0] + sh_acc[1][0][t] + sh_acc[1][1][t];
    if (t > 0)       lg += sh_acc[2][0][t - 1] + sh_acc[2][1][t - 1];
    if (t < NDD - 1) lg += sh_acc[0][0][t + 1] + sh_acc[0][1][t + 1];
    sh_l[t] = lg;
  }
  __syncthreads();
  if (tid < 64) {
    float v1 = sh_l[tid], v2 = sh_l[tid + 64];
    float mv; int mi;
    if (v2 > v1) { mv = v2; mi = tid + 64; } else { mv = v1; mi = tid; }  // tie -> lower index
#pragma unroll
    for (int off = 32; off >= 1; off >>= 1) {
      float ov = __shfl_xor(mv, off, 64);
      int   oi = __shfl_xor(mi, off, 64);
      if (ov > mv || (ov == mv && oi < mi)) { mv = ov; mi = oi; }
    }
    if (tid == 0) { sh_sc[0] = mv; ((int*)sh_sc)[1] = mi; }
  }
  __syncthreads();
  const float gmax = sh_sc[0];
  const int gidx = ((const int*)sh_sc)[1];
  if (tid < NDD) sh_e[tid] = expf(sh_l[tid] - gmax);
  __syncthreads();
  if (tid < 64) {
    float S = warp_red_sum(sh_e[tid] + sh_e[tid + 64]);
    float a1 = 0.0f, a2 = 0.0f;
#pragma unroll
    for (int k = 0; k < 2; ++k) {
      int t = tid + k * 64;
      float vol = sh_e[t] / S;
      float msk = (fabsf((float)t - (float)gidx) <= 5.0f) ? 1.0f : 0.0f;
      float mvv = vol * msk;
      a1 += mvv;
      a2 += mvv * (float)t;
    }
    a1 = warp_red_sum(a1);
    a2 = warp_red_sum(a2);
    if (tid == 0) {
      float pred = a2 / (a1 + 1e-8f);
      out[n] = pred / 127.0f * 6000.0f + 2000.0f;
    }
  }
}

extern "C" void kernel_launch(void* const* d_in, const int* in_sizes, int n_in,
                              void* d_out, int out_size, void* d_ws, size_t ws_size,
                              hipStream_t stream) {
  (void)in_sizes; (void)n_in; (void)out_size; (void)d_ws; (void)ws_size;
  const float* kpts        = (const float*)d_in[0];
  const float* joint_vis   = (const float*)d_in[2];
  const float* cam_R       = (const float*)d_in[5];
  const float* cam_T       = (const float*)d_in[6];
  const float* cam_f       = (const float*)d_in[7];
  const float* cam_c       = (const float*)d_in[8];
  const float* image_wh    = (const float*)d_in[9];
  const int*   num_persons = (const int*)d_in[10];
  const float* Wr1 = (const float*)d_in[11];
  const float* br1 = (const float*)d_in[12];
  const float* Wr2 = (const float*)d_in[13];
  const float* br2 = (const float*)d_in[14];
  const float* Wc1 = (const float*)d_in[15];
  const float* bc1 = (const float*)d_in[16];
  const float* Wc2 = (const float*)d_in[17];
  const float* bc2 = (const float*)d_in[18];
  float* out = (float*)d_out;

  hipLaunchKernelGGL(pose_fused_kernel, dim3(BB * NPP), dim3(256), 0, stream,
                     kpts, joint_vis, cam_R, cam_T, cam_f, cam_c, image_wh,
                     num_persons, Wr1, br1, Wr2, br2, Wc1, bc1, Wc2, bc2, out);
}

// Round 2
// 526.107 us; speedup vs baseline: 1.5372x; 1.5372x over previous
//
#include <hip/hip_runtime.h>
#include <math.h>

#define VV  5
#define BB  32
#define NPP 20
#define NJJ 17
#define NBB 16
#define NDD 128
#define HID 1024
#define OSPLIT 8
#define OCHUNK (HID / OSPLIT)          // 128 outputs per conv block
#define XIN_ELEMS (BB * NPP * (NJJ + NBB) * NDD)   // 640*33*128

static constexpr int BONE_A[NBB] = {0,0,1,2,5,5,7,6,8,5,6,11,11,13,12,14};
static constexpr int BONE_B[NBB] = {1,2,3,4,6,7,9,8,10,11,12,12,13,15,14,16};

__device__ __forceinline__ float warp_red_sum(float v) {
#pragma unroll
  for (int off = 32; off >= 1; off >>= 1) v += __shfl_xor(v, off, 64);
  return v;
}

// ===================== K1: geometry + matching -> xin =====================
__global__ __launch_bounds__(256) void pose_front_kernel(
    const float* __restrict__ kpts, const float* __restrict__ joint_vis,
    const float* __restrict__ cam_R, const float* __restrict__ cam_T,
    const float* __restrict__ cam_f, const float* __restrict__ cam_c,
    const float* __restrict__ image_wh, const int* __restrict__ num_persons,
    const float* __restrict__ Wr1, const float* __restrict__ br1,
    const float* __restrict__ Wr2, const float* __restrict__ br2,
    float* __restrict__ ws_xin) {
  const int n = blockIdx.x;
  const int b = n / NPP;
  const int p = n % NPP;
  const int tid = threadIdx.x;

  __shared__ float sh_x[NJJ * 2];
  __shared__ float sh_h[HID];
  __shared__ float sh_rough[NJJ];
  __shared__ float sh_base[NJJ][3];
  __shared__ float sh_pr[NPP * NJJ * 2];
  __shared__ float sh_vr[NPP * NJJ];

  // Phase 1a: normalized view-0 keypoints
  if (tid < NJJ * 2) {
    int j = tid >> 1, c = tid & 1;
    float k = kpts[((size_t)(b * NPP + p)) * NJJ * 2 + j * 2 + c];
    sh_x[tid] = k / image_wh[c];
  }
  __syncthreads();

  // Phase 1b: h = relu(x @ Wr1.T + br1)
#pragma unroll
  for (int k = 0; k < 4; ++k) {
    int m = tid + k * 256;
    float acc = br1[m];
#pragma unroll
    for (int c = 0; c < NJJ * 2; ++c) acc = fmaf(Wr1[m * (NJJ * 2) + c], sh_x[c], acc);
    sh_h[m] = fmaxf(acc, 0.0f);
  }
  __syncthreads();

  // Phase 1c (wave 0): rough depths; Phase 2 (wave 1): ray bases
  if (tid < 64) {
    for (int j = 0; j < NJJ; ++j) {
      float part = 0.0f;
      for (int m = tid; m < HID; m += 64) part = fmaf(Wr2[j * HID + m], sh_h[m], part);
      part = warp_red_sum(part);
      if (tid == 0) sh_rough[j] = (part + br2[j]) * 1000.0f;
    }
  } else if (tid < 64 + NJJ) {
    int j = tid - 64;
    const float* R0 = cam_R + (size_t)b * 9;
    float c0x = cam_c[b * 2 + 0], c0y = cam_c[b * 2 + 1];
    float f0x = cam_f[b * 2 + 0], f0y = cam_f[b * 2 + 1];
    float kx = kpts[((size_t)(b * NPP + p)) * NJJ * 2 + j * 2 + 0];
    float ky = kpts[((size_t)(b * NPP + p)) * NJJ * 2 + j * 2 + 1];
    float ux = (kx - c0x) / f0x;
    float uy = (ky - c0y) / f0y;
#pragma unroll
    for (int i = 0; i < 3; ++i)
      sh_base[j][i] = R0[0 * 3 + i] * ux + R0[1 * 3 + i] * uy + R0[2 * 3 + i];
  }
  __syncthreads();

  // Phase 3: per-view projection, matching, scoring
  float px[NJJ], py[NJJ];
  float sj[NJJ], bj[NJJ];
  float s2[NBB];
  float b2 = 0.0f;
#pragma unroll
  for (int j = 0; j < NJJ; ++j) { sj[j] = 0.0f; bj[j] = 0.0f; }
#pragma unroll
  for (int nb = 0; nb < NBB; ++nb) s2[nb] = 0.0f;

  const float T0x = cam_T[b * 3 + 0], T0y = cam_T[b * 3 + 1], T0z = cam_T[b * 3 + 2];
  const float lab = ((float)(tid & (NDD - 1)) / 127.0f) * 6000.0f + 2000.0f;

  for (int rv = 1; rv < VV; ++rv) {
    __syncthreads();
    {
      const float* prg = kpts + ((size_t)rv * BB + b) * NPP * NJJ * 2;
      for (int idx = tid; idx < NPP * NJJ * 2; idx += 256) sh_pr[idx] = prg[idx];
      const float* vrg = joint_vis + ((size_t)rv * BB + b) * NPP * NJJ;
      for (int idx = tid; idx < NPP * NJJ; idx += 256) sh_vr[idx] = vrg[idx];
    }
    __syncthreads();

    if (tid < NDD) {
      const int vb = rv * BB + b;
      const float* Rr = cam_R + (size_t)vb * 9;
      const float R00 = Rr[0], R01 = Rr[1], R02 = Rr[2];
      const float R10 = Rr[3], R11 = Rr[4], R12 = Rr[5];
      const float R20 = Rr[6], R21 = Rr[7], R22 = Rr[8];
      const float Trx = cam_T[vb * 3 + 0], Try = cam_T[vb * 3 + 1], Trz = cam_T[vb * 3 + 2];
      const float frx = cam_f[vb * 2 + 0], fry = cam_f[vb * 2 + 1];
      const float crx = cam_c[vb * 2 + 0], cry = cam_c[vb * 2 + 1];
      const float wmax = image_wh[vb * 2 + 0] - 1.0f;
      const float hmax = image_wh[vb * 2 + 1] - 1.0f;
      const int nprv = num_persons[vb];

#pragma unroll
      for (int j = 0; j < NJJ; ++j) {
        float dep = lab + sh_rough[j];
        float p0 = fmaf(dep, sh_base[j][0], T0x);
        float p1 = fmaf(dep, sh_base[j][1], T0y);
        float p2 = fmaf(dep, sh_base[j][2], T0z);
        float q0 = p0 - Trx, q1 = p1 - Try, q2 = p2 - Trz;
        float xc0 = R00 * q0 + R01 * q1 + R02 * q2;
        float xc1 = R10 * q0 + R11 * q1 + R12 * q2;
        float xc2 = R20 * q0 + R21 * q1 + R22 * q2 + 1e-8f;
        px[j] = xc0 / xc2 * frx + crx;
        py[j] = xc1 / xc2 * fry + cry;
      }

      float best = 3.4e38f;
      int mm = 0;
      for (int q = 0; q < NPP; ++q) {
        float num = 0.0f, den = 0.0f;
#pragma unroll
        for (int j = 0; j < NJJ; ++j) {
          float w = sh_vr[q * NJJ + j];
          float dx = px[j] - sh_pr[(q * NJJ + j) * 2 + 0];
          float dy = py[j] - sh_pr[(q * NJJ + j) * 2 + 1];
          num = fmaf(w, dx * dx + dy * dy, num);
          den += w;
        }
        float pd = num / (den + 1e-8f);
        if (q >= nprv) pd = 100000.0f;
        if (pd < best) { best = pd; mm = q; }
      }

#pragma unroll
      for (int j = 0; j < NJJ; ++j) {
        float mx = sh_pr[(mm * NJJ + j) * 2 + 0];
        float my = sh_pr[(mm * NJJ + j) * 2 + 1];
        float mv = sh_vr[mm * NJJ + j];
        float dx = px[j] - mx, dy = py[j] - my;
        float sc = expf(-sqrtf(dx * dx + dy * dy + 1e-12f) / 100.0f);
        float inb = (px[j] >= 0.0f && py[j] >= 0.0f && px[j] <= wmax && py[j] <= hmax) ? 1.0f : 0.0f;
        float bd = inb * mv;
        sj[j] = fmaf(sc, bd, sj[j]);
        bj[j] += bd;
      }
      float v0 = sh_vr[mm * NJJ + 0];
#pragma unroll
      for (int nb = 0; nb < NBB; ++nb) {
        const int a = BONE_A[nb], c = BONE_B[nb];
        float ax = sh_pr[(mm * NJJ + a) * 2 + 0], ay = sh_pr[(mm * NJJ + a) * 2 + 1];
        float cx = sh_pr[(mm * NJJ + c) * 2 + 0], cy = sh_pr[(mm * NJJ + c) * 2 + 1];
        float dmx = ax - cx, dmy = ay - cy;
        float blm = sqrtf(dmx * dmx + dmy * dmy + 1e-12f);
        float dpx = px[a] - px[c], dpy = py[a] - py[c];
        float blp = sqrtf(dpx * dpx + dpy * dpy + 1e-12f);
        float scb = expf(-fabsf(blm - blp) / 5.0f);
        s2[nb] = fmaf(scb, v0, s2[nb]);
      }
      b2 += v0;
    }
  }

  // Phase 4: write xin[n][33][128] to workspace (coalesced over t)
  if (tid < NDD) {
    float* xo = ws_xin + (size_t)n * (NJJ + NBB) * NDD + tid;
#pragma unroll
    for (int j = 0; j < NJJ; ++j) xo[j * NDD] = sj[j] / (bj[j] + 1e-8f);
    float den2 = b2 + 1e-8f;
#pragma unroll
    for (int nb = 0; nb < NBB; ++nb) xo[(NJJ + nb) * NDD] = s2[nb] / den2;
  }
}

// ===================== K2: conv1(relu)+conv2 partial logits =====================
__global__ __launch_bounds__(128) void conv_kernel(
    const float* __restrict__ ws_xin,
    const float* __restrict__ Wc1, const float* __restrict__ bc1,
    const float* __restrict__ Wc2,
    float* __restrict__ ws_partial) {
  const int n = blockIdx.x;      // sample
  const int oc = blockIdx.y;     // o-chunk
  const int t = threadIdx.x;     // depth bin 0..127

  __shared__ float sx[NJJ + NBB][NDD + 2];
  __shared__ float sh_m[NDD], sh_c[NDD], sh_p[NDD];

  // stage xin into LDS with zero-padded t-axis
  const float* xi = ws_xin + (size_t)n * (NJJ + NBB) * NDD;
#pragma unroll
  for (int i = 0; i < NJJ + NBB; ++i) sx[i][t + 1] = xi[i * NDD + t];
  if (t < NJJ + NBB) { sx[t][0] = 0.0f; sx[t][NDD + 1] = 0.0f; }
  __syncthreads();

  const int obase = oc * OCHUNK;
  float accM = 0.0f, accC = 0.0f, accP = 0.0f;
  for (int o4 = 0; o4 < OCHUNK; o4 += 4) {
    const int o = obase + o4;
    float h0 = bc1[o + 0], h1 = bc1[o + 1], h2 = bc1[o + 2], h3 = bc1[o + 3];
    const float* w0 = Wc1 + (size_t)(o + 0) * 99;
    const float* w1 = Wc1 + (size_t)(o + 1) * 99;
    const float* w2 = Wc1 + (size_t)(o + 2) * 99;
    const float* w3 = Wc1 + (size_t)(o + 3) * 99;
#pragma unroll
    for (int i = 0; i < NJJ + NBB; ++i) {
      float x0 = sx[i][t + 0];
      float x1 = sx[i][t + 1];
      float x2 = sx[i][t + 2];
      h0 = fmaf(w0[3 * i + 0], x0, h0); h0 = fmaf(w0[3 * i + 1], x1, h0); h0 = fmaf(w0[3 * i + 2], x2, h0);
      h1 = fmaf(w1[3 * i + 0], x0, h1); h1 = fmaf(w1[3 * i + 1], x1, h1); h1 = fmaf(w1[3 * i + 2], x2, h1);
      h2 = fmaf(w2[3 * i + 0], x0, h2); h2 = fmaf(w2[3 * i + 1], x1, h2); h2 = fmaf(w2[3 * i + 2], x2, h2);
      h3 = fmaf(w3[3 * i + 0], x0, h3); h3 = fmaf(w3[3 * i + 1], x1, h3); h3 = fmaf(w3[3 * i + 2], x2, h3);
    }
    h0 = fmaxf(h0, 0.0f); h1 = fmaxf(h1, 0.0f); h2 = fmaxf(h2, 0.0f); h3 = fmaxf(h3, 0.0f);
    accP = fmaf(h0, Wc2[(o + 0) * 3 + 0], accP); accP = fmaf(h1, Wc2[(o + 1) * 3 + 0], accP);
    accP = fmaf(h2, Wc2[(o + 2) * 3 + 0], accP); accP = fmaf(h3, Wc2[(o + 3) * 3 + 0], accP);
    accC = fmaf(h0, Wc2[(o + 0) * 3 + 1], accC); accC = fmaf(h1, Wc2[(o + 1) * 3 + 1], accC);
    accC = fmaf(h2, Wc2[(o + 2) * 3 + 1], accC); accC = fmaf(h3, Wc2[(o + 3) * 3 + 1], accC);
    accM = fmaf(h0, Wc2[(o + 0) * 3 + 2], accM); accM = fmaf(h1, Wc2[(o + 1) * 3 + 2], accM);
    accM = fmaf(h2, Wc2[(o + 2) * 3 + 2], accM); accM = fmaf(h3, Wc2[(o + 3) * 3 + 2], accM);
  }
  sh_m[t] = accM; sh_c[t] = accC; sh_p[t] = accP;
  __syncthreads();

  float lg = sh_c[t];
  if (t > 0)       lg += sh_p[t - 1];
  if (t < NDD - 1) lg += sh_m[t + 1];
  ws_partial[((size_t)oc * (BB * NPP) + n) * NDD + t] = lg;
}

// ===================== K3: sum partials + softmax + windowed readout =====================
__global__ __launch_bounds__(128) void readout_kernel(
    const float* __restrict__ ws_partial, const float* __restrict__ bc2,
    float* __restrict__ out) {
  const int n = blockIdx.x;
  const int t = threadIdx.x;

  __shared__ float sh_l[NDD];
  __shared__ float sh_e[NDD];
  __shared__ float sh_sc[2];

  float lg = bc2[0];
#pragma unroll
  for (int oc = 0; oc < OSPLIT; ++oc)
    lg += ws_partial[((size_t)oc * (BB * NPP) + n) * NDD + t];
  sh_l[t] = lg;
  __syncthreads();

  if (t < 64) {
    float v1 = sh_l[t], v2 = sh_l[t + 64];
    float mv; int mi;
    if (v2 > v1) { mv = v2; mi = t + 64; } else { mv = v1; mi = t; }
#pragma unroll
    for (int off = 32; off >= 1; off >>= 1) {
      float ov = __shfl_xor(mv, off, 64);
      int   oi = __shfl_xor(mi, off, 64);
      if (ov > mv || (ov == mv && oi < mi)) { mv = ov; mi = oi; }
    }
    if (t == 0) { sh_sc[0] = mv; ((int*)sh_sc)[1] = mi; }
  }
  __syncthreads();
  const float gmax = sh_sc[0];
  const int gidx = ((const int*)sh_sc)[1];
  sh_e[t] = expf(sh_l[t] - gmax);
  __syncthreads();
  if (t < 64) {
    float S = warp_red_sum(sh_e[t] + sh_e[t + 64]);
    float a1 = 0.0f, a2 = 0.0f;
#pragma unroll
    for (int k = 0; k < 2; ++k) {
      int tt = t + k * 64;
      float vol = sh_e[tt] / S;
      float msk = (fabsf((float)tt - (float)gidx) <= 5.0f) ? 1.0f : 0.0f;
      float mvv = vol * msk;
      a1 += mvv;
      a2 += mvv * (float)tt;
    }
    a1 = warp_red_sum(a1);
    a2 = warp_red_sum(a2);
    if (t == 0) {
      float pred = a2 / (a1 + 1e-8f);
      out[n] = pred / 127.0f * 6000.0f + 2000.0f;
    }
  }
}

extern "C" void kernel_launch(void* const* d_in, const int* in_sizes, int n_in,
                              void* d_out, int out_size, void* d_ws, size_t ws_size,
                              hipStream_t stream) {
  (void)in_sizes; (void)n_in; (void)out_size; (void)ws_size;
  const float* kpts        = (const float*)d_in[0];
  const float* joint_vis   = (const float*)d_in[2];
  const float* cam_R       = (const float*)d_in[5];
  const float* cam_T       = (const float*)d_in[6];
  const float* cam_f       = (const float*)d_in[7];
  const float* cam_c       = (const float*)d_in[8];
  const float* image_wh    = (const float*)d_in[9];
  const int*   num_persons = (const int*)d_in[10];
  const float* Wr1 = (const float*)d_in[11];
  const float* br1 = (const float*)d_in[12];
  const float* Wr2 = (const float*)d_in[13];
  const float* br2 = (const float*)d_in[14];
  const float* Wc1 = (const float*)d_in[15];
  const float* bc1 = (const float*)d_in[16];
  const float* Wc2 = (const float*)d_in[17];
  const float* bc2 = (const float*)d_in[18];
  float* out = (float*)d_out;

  float* ws_xin     = (float*)d_ws;
  float* ws_partial = ws_xin + XIN_ELEMS;

  hipLaunchKernelGGL(pose_front_kernel, dim3(BB * NPP), dim3(256), 0, stream,
                     kpts, joint_vis, cam_R, cam_T, cam_f, cam_c, image_wh,
                     num_persons, Wr1, br1, Wr2, br2, ws_xin);
  hipLaunchKernelGGL(conv_kernel, dim3(BB * NPP, OSPLIT), dim3(128), 0, stream,
                     ws_xin, Wc1, bc1, Wc2, ws_partial);
  hipLaunchKernelGGL(readout_kernel, dim3(BB * NPP), dim3(128), 0, stream,
                     ws_partial, bc2, out);
}

// Round 3
// 314.219 us; speedup vs baseline: 2.5738x; 1.6743x over previous
//
#include <hip/hip_runtime.h>
#include <math.h>

#define VV  5
#define BB  32
#define NPP 20
#define NJJ 17
#define NBB 16
#define NDD 128
#define HID 1024
#define KPITCH 128          // padded kappa pitch (elements)
#define KSTEPS 7            // 7 * 16 = 112 >= 99

typedef __attribute__((ext_vector_type(8))) short short8;
typedef __attribute__((ext_vector_type(16))) float float16;

static constexpr int BONE_A[NBB] = {0,0,1,2,5,5,7,6,8,5,6,11,11,13,12,14};
static constexpr int BONE_B[NBB] = {1,2,3,4,6,7,9,8,10,11,12,12,13,15,14,16};

__device__ __forceinline__ float warp_red_sum(float v) {
#pragma unroll
  for (int off = 32; off >= 1; off >>= 1) v += __shfl_xor(v, off, 64);
  return v;
}

// ============ K0: split Wc1 into bf16 hi/lo, kappa-padded [1024][128] ============
__global__ __launch_bounds__(256) void prep_kernel(
    const float* __restrict__ Wc1, unsigned short* __restrict__ A_hi,
    unsigned short* __restrict__ A_lo) {
  int idx = blockIdx.x * 256 + threadIdx.x;    // over 1024*128
  int o = idx >> 7, kk = idx & 127;
  float x = (kk < 99) ? Wc1[o * 99 + kk] : 0.0f;
  unsigned int u = __float_as_uint(x);
  unsigned short hi = (unsigned short)(u >> 16);
  float xh = __uint_as_float((u >> 16) << 16);
  float r = x - xh;
  unsigned short lo = (unsigned short)(__float_as_uint(r) >> 16);
  A_hi[idx] = hi;
  A_lo[idx] = lo;
}

// ===================== K1: geometry + matching -> xin =====================
__global__ __launch_bounds__(256) void pose_front_kernel(
    const float* __restrict__ kpts, const float* __restrict__ joint_vis,
    const float* __restrict__ cam_R, const float* __restrict__ cam_T,
    const float* __restrict__ cam_f, const float* __restrict__ cam_c,
    const float* __restrict__ image_wh, const int* __restrict__ num_persons,
    const float* __restrict__ Wr1, const float* __restrict__ br1,
    const float* __restrict__ Wr2, const float* __restrict__ br2,
    float* __restrict__ ws_xin) {
  const int n = blockIdx.x;
  const int b = n / NPP;
  const int p = n % NPP;
  const int tid = threadIdx.x;

  __shared__ float sh_x[NJJ * 2];
  __shared__ float sh_h[HID];
  __shared__ float sh_rough[NJJ];
  __shared__ float sh_base[NJJ][3];
  __shared__ float sh_pr[NPP * NJJ * 2];
  __shared__ float sh_vr[NPP * NJJ];

  if (tid < NJJ * 2) {
    int j = tid >> 1, c = tid & 1;
    float k = kpts[((size_t)(b * NPP + p)) * NJJ * 2 + j * 2 + c];
    sh_x[tid] = k / image_wh[c];
  }
  __syncthreads();

#pragma unroll
  for (int k = 0; k < 4; ++k) {
    int m = tid + k * 256;
    float acc = br1[m];
#pragma unroll
    for (int c = 0; c < NJJ * 2; ++c) acc = fmaf(Wr1[m * (NJJ * 2) + c], sh_x[c], acc);
    sh_h[m] = fmaxf(acc, 0.0f);
  }
  __syncthreads();

  if (tid < 64) {
    for (int j = 0; j < NJJ; ++j) {
      float part = 0.0f;
      for (int m = tid; m < HID; m += 64) part = fmaf(Wr2[j * HID + m], sh_h[m], part);
      part = warp_red_sum(part);
      if (tid == 0) sh_rough[j] = (part + br2[j]) * 1000.0f;
    }
  } else if (tid < 64 + NJJ) {
    int j = tid - 64;
    const float* R0 = cam_R + (size_t)b * 9;
    float c0x = cam_c[b * 2 + 0], c0y = cam_c[b * 2 + 1];
    float f0x = cam_f[b * 2 + 0], f0y = cam_f[b * 2 + 1];
    float kx = kpts[((size_t)(b * NPP + p)) * NJJ * 2 + j * 2 + 0];
    float ky = kpts[((size_t)(b * NPP + p)) * NJJ * 2 + j * 2 + 1];
    float ux = (kx - c0x) / f0x;
    float uy = (ky - c0y) / f0y;
#pragma unroll
    for (int i = 0; i < 3; ++i)
      sh_base[j][i] = R0[0 * 3 + i] * ux + R0[1 * 3 + i] * uy + R0[2 * 3 + i];
  }
  __syncthreads();

  float px[NJJ], py[NJJ];
  float sj[NJJ], bj[NJJ];
  float s2[NBB];
  float b2 = 0.0f;
#pragma unroll
  for (int j = 0; j < NJJ; ++j) { sj[j] = 0.0f; bj[j] = 0.0f; }
#pragma unroll
  for (int nb = 0; nb < NBB; ++nb) s2[nb] = 0.0f;

  const float T0x = cam_T[b * 3 + 0], T0y = cam_T[b * 3 + 1], T0z = cam_T[b * 3 + 2];
  const float lab = ((float)(tid & (NDD - 1)) / 127.0f) * 6000.0f + 2000.0f;

  for (int rv = 1; rv < VV; ++rv) {
    __syncthreads();
    {
      const float* prg = kpts + ((size_t)rv * BB + b) * NPP * NJJ * 2;
      for (int idx = tid; idx < NPP * NJJ * 2; idx += 256) sh_pr[idx] = prg[idx];
      const float* vrg = joint_vis + ((size_t)rv * BB + b) * NPP * NJJ;
      for (int idx = tid; idx < NPP * NJJ; idx += 256) sh_vr[idx] = vrg[idx];
    }
    __syncthreads();

    if (tid < NDD) {
      const int vb = rv * BB + b;
      const float* Rr = cam_R + (size_t)vb * 9;
      const float R00 = Rr[0], R01 = Rr[1], R02 = Rr[2];
      const float R10 = Rr[3], R11 = Rr[4], R12 = Rr[5];
      const float R20 = Rr[6], R21 = Rr[7], R22 = Rr[8];
      const float Trx = cam_T[vb * 3 + 0], Try = cam_T[vb * 3 + 1], Trz = cam_T[vb * 3 + 2];
      const float frx = cam_f[vb * 2 + 0], fry = cam_f[vb * 2 + 1];
      const float crx = cam_c[vb * 2 + 0], cry = cam_c[vb * 2 + 1];
      const float wmax = image_wh[vb * 2 + 0] - 1.0f;
      const float hmax = image_wh[vb * 2 + 1] - 1.0f;
      const int nprv = num_persons[vb];

#pragma unroll
      for (int j = 0; j < NJJ; ++j) {
        float dep = lab + sh_rough[j];
        float p0 = fmaf(dep, sh_base[j][0], T0x);
        float p1 = fmaf(dep, sh_base[j][1], T0y);
        float p2 = fmaf(dep, sh_base[j][2], T0z);
        float q0 = p0 - Trx, q1 = p1 - Try, q2 = p2 - Trz;
        float xc0 = R00 * q0 + R01 * q1 + R02 * q2;
        float xc1 = R10 * q0 + R11 * q1 + R12 * q2;
        float xc2 = R20 * q0 + R21 * q1 + R22 * q2 + 1e-8f;
        px[j] = xc0 / xc2 * frx + crx;
        py[j] = xc1 / xc2 * fry + cry;
      }

      float best = 3.4e38f;
      int mm = 0;
      for (int q = 0; q < NPP; ++q) {
        float num = 0.0f, den = 0.0f;
#pragma unroll
        for (int j = 0; j < NJJ; ++j) {
          float w = sh_vr[q * NJJ + j];
          float dx = px[j] - sh_pr[(q * NJJ + j) * 2 + 0];
          float dy = py[j] - sh_pr[(q * NJJ + j) * 2 + 1];
          num = fmaf(w, dx * dx + dy * dy, num);
          den += w;
        }
        float pd = num / (den + 1e-8f);
        if (q >= nprv) pd = 100000.0f;
        if (pd < best) { best = pd; mm = q; }
      }

#pragma unroll
      for (int j = 0; j < NJJ; ++j) {
        float mx = sh_pr[(mm * NJJ + j) * 2 + 0];
        float my = sh_pr[(mm * NJJ + j) * 2 + 1];
        float mv = sh_vr[mm * NJJ + j];
        float dx = px[j] - mx, dy = py[j] - my;
        float sc = expf(-sqrtf(dx * dx + dy * dy + 1e-12f) / 100.0f);
        float inb = (px[j] >= 0.0f && py[j] >= 0.0f && px[j] <= wmax && py[j] <= hmax) ? 1.0f : 0.0f;
        float bd = inb * mv;
        sj[j] = fmaf(sc, bd, sj[j]);
        bj[j] += bd;
      }
      float v0 = sh_vr[mm * NJJ + 0];
#pragma unroll
      for (int nb = 0; nb < NBB; ++nb) {
        const int a = BONE_A[nb], c = BONE_B[nb];
        float ax = sh_pr[(mm * NJJ + a) * 2 + 0], ay = sh_pr[(mm * NJJ + a) * 2 + 1];
        float cx = sh_pr[(mm * NJJ + c) * 2 + 0], cy = sh_pr[(mm * NJJ + c) * 2 + 1];
        float dmx = ax - cx, dmy = ay - cy;
        float blm = sqrtf(dmx * dmx + dmy * dmy + 1e-12f);
        float dpx = px[a] - px[c], dpy = py[a] - py[c];
        float blp = sqrtf(dpx * dpx + dpy * dpy + 1e-12f);
        float scb = expf(-fabsf(blm - blp) / 5.0f);
        s2[nb] = fmaf(scb, v0, s2[nb]);
      }
      b2 += v0;
    }
  }

  if (tid < NDD) {
    float* xo = ws_xin + (size_t)n * (NJJ + NBB) * NDD + tid;
#pragma unroll
    for (int j = 0; j < NJJ; ++j) xo[j * NDD] = sj[j] / (bj[j] + 1e-8f);
    float den2 = b2 + 1e-8f;
#pragma unroll
    for (int nb = 0; nb < NBB; ++nb) xo[(NJJ + nb) * NDD] = s2[nb] / den2;
  }
}

// ============ K2: MFMA split-bf16 conv1 + fused conv2 + softmax readout ============
__global__ __launch_bounds__(512, 2) void conv_mfma_kernel(
    const float* __restrict__ ws_xin,
    const unsigned short* __restrict__ A_hi, const unsigned short* __restrict__ A_lo,
    const float* __restrict__ bc1, const float* __restrict__ Wc2,
    const float* __restrict__ bc2, float* __restrict__ out) {
  const int n = blockIdx.x;
  const int tid = threadIdx.x;
  const int w = tid >> 6;     // wave 0..7
  const int l = tid & 63;     // lane
  const int lrow = l & 31;    // A-row / B-col (t) lane index
  const int g = l >> 5;       // k-half

  __shared__ __align__(16) unsigned short bT_hi[128 * KPITCH];  // swizzled [t][kappa]
  __shared__ __align__(16) unsigned short bT_lo[128 * KPITCH];
  __shared__ float plg[3][8][NDD];   // [P,C,M][wave][t] partial logits
  __shared__ float sh_l[NDD];
  __shared__ float sh_e[NDD];
  __shared__ float sh_sc[2];

  // zero partial logits
  for (int i = tid; i < 3 * 8 * NDD; i += 512) ((float*)plg)[i] = 0.0f;

  // ---- build swizzled split-bf16 im2col in LDS: B[kappa][t] = xin[i][t+k-1] ----
  const float* xn = ws_xin + (size_t)n * (NJJ + NBB) * NDD;
  for (int idx = tid; idx < 112 * 128; idx += 512) {
    int kk = idx >> 7;          // kappa
    int t  = idx & 127;
    float x = 0.0f;
    if (kk < 99) {
      int i3 = kk / 3;
      int k3 = kk - i3 * 3;
      int tt = t + k3 - 1;
      if (tt >= 0 && tt < 128) x = xn[i3 * NDD + tt];
    }
    unsigned int u = __float_as_uint(x);
    unsigned short hi = (unsigned short)(u >> 16);
    float xh = __uint_as_float((u >> 16) << 16);
    unsigned short lo = (unsigned short)(__float_as_uint(x - xh) >> 16);
    int eoff = t * KPITCH + (kk ^ ((t & 15) << 3));   // XOR swizzle (16B granules)
    bT_hi[eoff] = hi;
    bT_lo[eoff] = lo;
  }
  __syncthreads();

  // ---- main: per wave 4 o-tiles (32 rows each), per o-tile 4 t-tiles ----
#pragma unroll 1
  for (int otile = 0; otile < 4; ++otile) {
    const int o0 = w * 128 + otile * 32;

    // A fragments held in registers across the t-loop
    short8 Ah[KSTEPS], Al[KSTEPS];
    {
      const unsigned short* arh = A_hi + (size_t)(o0 + lrow) * KPITCH + g * 8;
      const unsigned short* arl = A_lo + (size_t)(o0 + lrow) * KPITCH + g * 8;
#pragma unroll
      for (int ks = 0; ks < KSTEPS; ++ks) {
        Ah[ks] = *(const short8*)(arh + ks * 16);
        Al[ks] = *(const short8*)(arl + ks * 16);
      }
    }
    // per-lane Wc2 / bc1 for this o-tile: o_r = o0 + 4*g + 8*rb + (r&3)
    float w2f[48];
    float bcf[16];
#pragma unroll
    for (int rb = 0; rb < 4; ++rb) {
      int base = o0 + 4 * g + 8 * rb;
      float4 wa = *(const float4*)(Wc2 + base * 3 + 0);
      float4 wb = *(const float4*)(Wc2 + base * 3 + 4);
      float4 wc = *(const float4*)(Wc2 + base * 3 + 8);
      w2f[rb * 12 + 0] = wa.x;  w2f[rb * 12 + 1] = wa.y;  w2f[rb * 12 + 2] = wa.z;
      w2f[rb * 12 + 3] = wa.w;  w2f[rb * 12 + 4] = wb.x;  w2f[rb * 12 + 5] = wb.y;
      w2f[rb * 12 + 6] = wb.z;  w2f[rb * 12 + 7] = wb.w;  w2f[rb * 12 + 8] = wc.x;
      w2f[rb * 12 + 9] = wc.y;  w2f[rb * 12 + 10] = wc.z; w2f[rb * 12 + 11] = wc.w;
      float4 bb = *(const float4*)(bc1 + base);
      bcf[rb * 4 + 0] = bb.x; bcf[rb * 4 + 1] = bb.y;
      bcf[rb * 4 + 2] = bb.z; bcf[rb * 4 + 3] = bb.w;
    }

#pragma unroll 1
    for (int ttile = 0; ttile < 4; ++ttile) {
      const int trow = ttile * 32 + lrow;     // this lane's t column
      float16 acc;
#pragma unroll
      for (int r = 0; r < 16; ++r) acc[r] = 0.0f;

      const unsigned short* brh = bT_hi + trow * KPITCH;
      const unsigned short* brl = bT_lo + trow * KPITCH;
      const int sw = (trow & 15) << 3;
#pragma unroll
      for (int ks = 0; ks < KSTEPS; ++ks) {
        int eoff = (ks * 16 + g * 8) ^ sw;
        short8 bh = *(const short8*)(brh + eoff);
        short8 bl = *(const short8*)(brl + eoff);
        acc = __builtin_amdgcn_mfma_f32_32x32x16_bf16(Ah[ks], bh, acc, 0, 0, 0);
        acc = __builtin_amdgcn_mfma_f32_32x32x16_bf16(Al[ks], bh, acc, 0, 0, 0);
        acc = __builtin_amdgcn_mfma_f32_32x32x16_bf16(Ah[ks], bl, acc, 0, 0, 0);
      }

      // epilogue: bias+relu, conv2 per-lane partials
      float sP = 0.0f, sC = 0.0f, sM = 0.0f;
#pragma unroll
      for (int r = 0; r < 16; ++r) {
        float h = fmaxf(acc[r] + bcf[(r >> 2) * 4 + (r & 3)], 0.0f);
        sP = fmaf(h, w2f[(r >> 2) * 12 + (r & 3) * 3 + 0], sP);
        sC = fmaf(h, w2f[(r >> 2) * 12 + (r & 3) * 3 + 1], sC);
        sM = fmaf(h, w2f[(r >> 2) * 12 + (r & 3) * 3 + 2], sM);
      }
      sP += __shfl_xor(sP, 32, 64);
      sC += __shfl_xor(sC, 32, 64);
      sM += __shfl_xor(sM, 32, 64);
      if (l < 32) {
        plg[0][w][trow] += sP;
        plg[1][w][trow] += sC;
        plg[2][w][trow] += sM;
      }
    }
  }
  __syncthreads();

  // ---- logits + softmax + windowed argmax readout ----
  if (tid < NDD) {
    int t = tid;
    float lg = bc2[0];
#pragma unroll
    for (int ww = 0; ww < 8; ++ww) lg += plg[1][ww][t];
    if (t > 0) {
#pragma unroll
      for (int ww = 0; ww < 8; ++ww) lg += plg[0][ww][t - 1];
    }
    if (t < NDD - 1) {
#pragma unroll
      for (int ww = 0; ww < 8; ++ww) lg += plg[2][ww][t + 1];
    }
    sh_l[t] = lg;
  }
  __syncthreads();
  if (tid < 64) {
    float v1 = sh_l[tid], v2 = sh_l[tid + 64];
    float mv; int mi;
    if (v2 > v1) { mv = v2; mi = tid + 64; } else { mv = v1; mi = tid; }
#pragma unroll
    for (int off = 32; off >= 1; off >>= 1) {
      float ov = __shfl_xor(mv, off, 64);
      int   oi = __shfl_xor(mi, off, 64);
      if (ov > mv || (ov == mv && oi < mi)) { mv = ov; mi = oi; }
    }
    if (tid == 0) { sh_sc[0] = mv; ((int*)sh_sc)[1] = mi; }
  }
  __syncthreads();
  const float gmax = sh_sc[0];
  const int gidx = ((const int*)sh_sc)[1];
  if (tid < NDD) sh_e[tid] = expf(sh_l[tid] - gmax);
  __syncthreads();
  if (tid < 64) {
    float S = warp_red_sum(sh_e[tid] + sh_e[tid + 64]);
    float a1 = 0.0f, a2 = 0.0f;
#pragma unroll
    for (int k = 0; k < 2; ++k) {
      int t = tid + k * 64;
      float vol = sh_e[t] / S;
      float msk = (fabsf((float)t - (float)gidx) <= 5.0f) ? 1.0f : 0.0f;
      float mvv = vol * msk;
      a1 += mvv;
      a2 += mvv * (float)t;
    }
    a1 = warp_red_sum(a1);
    a2 = warp_red_sum(a2);
    if (tid == 0) {
      float pred = a2 / (a1 + 1e-8f);
      out[n] = pred / 127.0f * 6000.0f + 2000.0f;
    }
  }
}

extern "C" void kernel_launch(void* const* d_in, const int* in_sizes, int n_in,
                              void* d_out, int out_size, void* d_ws, size_t ws_size,
                              hipStream_t stream) {
  (void)in_sizes; (void)n_in; (void)out_size; (void)ws_size;
  const float* kpts        = (const float*)d_in[0];
  const float* joint_vis   = (const float*)d_in[2];
  const float* cam_R       = (const float*)d_in[5];
  const float* cam_T       = (const float*)d_in[6];
  const float* cam_f       = (const float*)d_in[7];
  const float* cam_c       = (const float*)d_in[8];
  const float* image_wh    = (const float*)d_in[9];
  const int*   num_persons = (const int*)d_in[10];
  const float* Wr1 = (const float*)d_in[11];
  const float* br1 = (const float*)d_in[12];
  const float* Wr2 = (const float*)d_in[13];
  const float* br2 = (const float*)d_in[14];
  const float* Wc1 = (const float*)d_in[15];
  const float* bc1 = (const float*)d_in[16];
  const float* Wc2 = (const float*)d_in[17];
  const float* bc2 = (const float*)d_in[18];
  float* out = (float*)d_out;

  unsigned short* A_hi = (unsigned short*)d_ws;              // 1024*128 u16
  unsigned short* A_lo = A_hi + HID * KPITCH;                // 1024*128 u16
  float* ws_xin = (float*)(A_lo + HID * KPITCH);             // 640*33*128 f32

  hipLaunchKernelGGL(prep_kernel, dim3((HID * KPITCH) / 256), dim3(256), 0, stream,
                     Wc1, A_hi, A_lo);
  hipLaunchKernelGGL(pose_front_kernel, dim3(BB * NPP), dim3(256), 0, stream,
                     kpts, joint_vis, cam_R, cam_T, cam_f, cam_c, image_wh,
                     num_persons, Wr1, br1, Wr2, br2, ws_xin);
  hipLaunchKernelGGL(conv_mfma_kernel, dim3(BB * NPP), dim3(512), 0, stream,
                     ws_xin, A_hi, A_lo, bc1, Wc2, bc2, out);
}

// Round 4
// 193.047 us; speedup vs baseline: 4.1894x; 1.6277x over previous
//
#include <hip/hip_runtime.h>
#include <math.h>

#define VV  5
#define BB  32
#define NPP 20
#define NJJ 17
#define NBB 16
#define NDD 128
#define HID 1024
#define KPITCH 128          // padded kappa pitch (elements)
#define KSTEPS 7            // 7 * 16 = 112 >= 99

typedef __attribute__((ext_vector_type(8))) short short8;
typedef __attribute__((ext_vector_type(16))) float float16;

static constexpr int BONE_A[NBB] = {0,0,1,2,5,5,7,6,8,5,6,11,11,13,12,14};
static constexpr int BONE_B[NBB] = {1,2,3,4,6,7,9,8,10,11,12,12,13,15,14,16};

__device__ __forceinline__ float warp_red_sum(float v) {
#pragma unroll
  for (int off = 32; off >= 1; off >>= 1) v += __shfl_xor(v, off, 64);
  return v;
}

// ============ K0: split Wc1 into bf16 hi/lo, kappa-padded [1024][128] ============
__global__ __launch_bounds__(256) void prep_kernel(
    const float* __restrict__ Wc1, unsigned short* __restrict__ A_hi,
    unsigned short* __restrict__ A_lo) {
  int idx = blockIdx.x * 256 + threadIdx.x;    // over 1024*128
  int o = idx >> 7, kk = idx & 127;
  float x = (kk < 99) ? Wc1[o * 99 + kk] : 0.0f;
  unsigned int u = __float_as_uint(x);
  unsigned short hi = (unsigned short)(u >> 16);
  float xh = __uint_as_float((u >> 16) << 16);
  float r = x - xh;
  unsigned short lo = (unsigned short)(__float_as_uint(r) >> 16);
  A_hi[idx] = hi;
  A_lo[idx] = lo;
}

// ===================== K1: geometry + matching -> xin =====================
// 512 threads: thread = (rvv = tid>>7 in 0..3 -> ref view rvv+1, d = tid&127).
__global__ __launch_bounds__(512) void pose_front_kernel(
    const float* __restrict__ kpts, const float* __restrict__ joint_vis,
    const float* __restrict__ cam_R, const float* __restrict__ cam_T,
    const float* __restrict__ cam_f, const float* __restrict__ cam_c,
    const float* __restrict__ image_wh, const int* __restrict__ num_persons,
    const float* __restrict__ Wr1, const float* __restrict__ br1,
    const float* __restrict__ Wr2, const float* __restrict__ br2,
    float* __restrict__ ws_xin) {
  const int n = blockIdx.x;
  const int b = n / NPP;
  const int p = n % NPP;
  const int tid = threadIdx.x;
  const int wv = tid >> 6, ln = tid & 63;
  const int rvv = tid >> 7;          // 0..3 -> view rvv+1
  const int d   = tid & (NDD - 1);   // depth bin

  __shared__ float sh_x[NJJ * 2];
  __shared__ float sh_h[HID];
  __shared__ float sh_rough[NJJ];
  __shared__ float sh_base[NJJ][3];
  __shared__ float sh_pr[4][NPP * NJJ * 2];
  __shared__ float sh_vr[4][NPP * NJJ];
  __shared__ float sh_stage[4][8][NDD];
  __shared__ float sh_s2red[NBB][NDD];

  // Phase 1a: normalized view-0 keypoints
  if (tid < NJJ * 2) {
    int j = tid >> 1, c = tid & 1;
    float k = kpts[((size_t)(b * NPP + p)) * NJJ * 2 + j * 2 + c];
    sh_x[tid] = k / image_wh[c];
  }
  __syncthreads();

  // Phase 1b: h = relu(x @ Wr1.T + br1), 2 rows/thread
#pragma unroll
  for (int k = 0; k < 2; ++k) {
    int m = tid + k * 512;
    float acc = br1[m];
#pragma unroll
    for (int c = 0; c < NJJ * 2; ++c) acc = fmaf(Wr1[m * (NJJ * 2) + c], sh_x[c], acc);
    sh_h[m] = fmaxf(acc, 0.0f);
  }
  __syncthreads();

  // Phase 1c: rough depths, 17 joints over 8 waves (same per-j math as before)
  for (int j = wv; j < NJJ; j += 8) {
    float part = 0.0f;
    for (int m = ln; m < HID; m += 64) part = fmaf(Wr2[j * HID + m], sh_h[m], part);
    part = warp_red_sum(part);
    if (ln == 0) sh_rough[j] = (part + br2[j]) * 1000.0f;
  }
  // Phase 2: ray bases
  if (tid < NJJ) {
    int j = tid;
    const float* R0 = cam_R + (size_t)b * 9;
    float c0x = cam_c[b * 2 + 0], c0y = cam_c[b * 2 + 1];
    float f0x = cam_f[b * 2 + 0], f0y = cam_f[b * 2 + 1];
    float kx = kpts[((size_t)(b * NPP + p)) * NJJ * 2 + j * 2 + 0];
    float ky = kpts[((size_t)(b * NPP + p)) * NJJ * 2 + j * 2 + 1];
    float ux = (kx - c0x) / f0x;
    float uy = (ky - c0y) / f0y;
#pragma unroll
    for (int i = 0; i < 3; ++i)
      sh_base[j][i] = R0[0 * 3 + i] * ux + R0[1 * 3 + i] * uy + R0[2 * 3 + i];
  }
  // Stage all 4 ref views' keypoints + visibility
#pragma unroll
  for (int rr = 0; rr < 4; ++rr) {
    const float* prg = kpts + ((size_t)(rr + 1) * BB + b) * NPP * NJJ * 2;
    for (int idx = tid; idx < NPP * NJJ * 2; idx += 512) sh_pr[rr][idx] = prg[idx];
    const float* vrg = joint_vis + ((size_t)(rr + 1) * BB + b) * NPP * NJJ;
    for (int idx = tid; idx < NPP * NJJ; idx += 512) sh_vr[rr][idx] = vrg[idx];
  }
  __syncthreads();

  // Phase 3: one (view, depth) per thread
  float partA[NJJ], partB[NJJ];   // sc*bd, bd
  float partS[NBB];               // scb*v0
  float partb2;                   // v0
  {
    const int rv = rvv + 1;
    const int vb = rv * BB + b;
    const float* Rr = cam_R + (size_t)vb * 9;
    const float R00 = Rr[0], R01 = Rr[1], R02 = Rr[2];
    const float R10 = Rr[3], R11 = Rr[4], R12 = Rr[5];
    const float R20 = Rr[6], R21 = Rr[7], R22 = Rr[8];
    const float Trx = cam_T[vb * 3 + 0], Try = cam_T[vb * 3 + 1], Trz = cam_T[vb * 3 + 2];
    const float frx = cam_f[vb * 2 + 0], fry = cam_f[vb * 2 + 1];
    const float crx = cam_c[vb * 2 + 0], cry = cam_c[vb * 2 + 1];
    const float wmax = image_wh[vb * 2 + 0] - 1.0f;
    const float hmax = image_wh[vb * 2 + 1] - 1.0f;
    const int nprv = num_persons[vb];
    const float T0x = cam_T[b * 3 + 0], T0y = cam_T[b * 3 + 1], T0z = cam_T[b * 3 + 2];
    const float lab = ((float)d / 127.0f) * 6000.0f + 2000.0f;
    const float* pr = sh_pr[rvv];
    const float* vr = sh_vr[rvv];

    float px[NJJ], py[NJJ];
#pragma unroll
    for (int j = 0; j < NJJ; ++j) {
      float dep = lab + sh_rough[j];
      float p0 = fmaf(dep, sh_base[j][0], T0x);
      float p1 = fmaf(dep, sh_base[j][1], T0y);
      float p2 = fmaf(dep, sh_base[j][2], T0z);
      float q0 = p0 - Trx, q1 = p1 - Try, q2 = p2 - Trz;
      float xc0 = R00 * q0 + R01 * q1 + R02 * q2;
      float xc1 = R10 * q0 + R11 * q1 + R12 * q2;
      float xc2 = R20 * q0 + R21 * q1 + R22 * q2 + 1e-8f;
      px[j] = xc0 / xc2 * frx + crx;
      py[j] = xc1 / xc2 * fry + cry;
    }

    float best = 3.4e38f;
    int mm = 0;
    for (int q = 0; q < NPP; ++q) {
      float num = 0.0f, den = 0.0f;
#pragma unroll
      for (int j = 0; j < NJJ; ++j) {
        float w = vr[q * NJJ + j];
        float dx = px[j] - pr[(q * NJJ + j) * 2 + 0];
        float dy = py[j] - pr[(q * NJJ + j) * 2 + 1];
        num = fmaf(w, dx * dx + dy * dy, num);
        den += w;
      }
      float pd = num / (den + 1e-8f);
      if (q >= nprv) pd = 100000.0f;
      if (pd < best) { best = pd; mm = q; }
    }

#pragma unroll
    for (int j = 0; j < NJJ; ++j) {
      float mx = pr[(mm * NJJ + j) * 2 + 0];
      float my = pr[(mm * NJJ + j) * 2 + 1];
      float mv = vr[mm * NJJ + j];
      float dx = px[j] - mx, dy = py[j] - my;
      float sc = expf(-sqrtf(dx * dx + dy * dy + 1e-12f) / 100.0f);
      float inb = (px[j] >= 0.0f && py[j] >= 0.0f && px[j] <= wmax && py[j] <= hmax) ? 1.0f : 0.0f;
      float bd = inb * mv;
      partA[j] = sc * bd;
      partB[j] = bd;
    }
    float v0 = vr[mm * NJJ + 0];
#pragma unroll
    for (int nb = 0; nb < NBB; ++nb) {
      const int a = BONE_A[nb], c = BONE_B[nb];
      float ax = pr[(mm * NJJ + a) * 2 + 0], ay = pr[(mm * NJJ + a) * 2 + 1];
      float cx = pr[(mm * NJJ + c) * 2 + 0], cy = pr[(mm * NJJ + c) * 2 + 1];
      float dmx = ax - cx, dmy = ay - cy;
      float blm = sqrtf(dmx * dmx + dmy * dmy + 1e-12f);
      float dpx = px[a] - px[c], dpy = py[a] - py[c];
      float blp = sqrtf(dpx * dpx + dpy * dpy + 1e-12f);
      float scb = expf(-fabsf(blm - blp) / 5.0f);
      partS[nb] = scb * v0;
    }
    partb2 = v0;
  }

  // Phase 4: deterministic cross-view reduction in rounds of 8 channels.
  // ch layout: 0..33 = (sj0,bj0,...,sj16,bj16); 34..49 = s2[0..15]; 50 = b2.
  float* xo = ws_xin + (size_t)n * (NJJ + NBB) * NDD;
#pragma unroll
  for (int r = 0; r < 7; ++r) {
#pragma unroll
    for (int i = 0; i < 8; ++i) {
      const int ch = r * 8 + i;
      if (ch <= 50) {
        float v;
        if (ch < 34) v = (ch & 1) ? partB[ch >> 1] : partA[ch >> 1];
        else if (ch < 50) v = partS[ch - 34];
        else v = partb2;
        sh_stage[rvv][i][d] = v;
      }
    }
    __syncthreads();
    if (tid < NDD) {
      float sjv = 0.0f;
#pragma unroll
      for (int i = 0; i < 8; ++i) {
        const int ch = r * 8 + i;
        if (ch > 50) continue;
        float s = ((sh_stage[0][i][tid] + sh_stage[1][i][tid]) + sh_stage[2][i][tid]) + sh_stage[3][i][tid];
        if (ch < 34) {
          if ((ch & 1) == 0) sjv = s;
          else xo[(ch >> 1) * NDD + tid] = sjv / (s + 1e-8f);
        } else if (ch < 50) {
          sh_s2red[ch - 34][tid] = s;
        } else {
          float den2 = s + 1e-8f;
#pragma unroll
          for (int nb = 0; nb < NBB; ++nb)
            xo[(NJJ + nb) * NDD + tid] = sh_s2red[nb][tid] / den2;
        }
      }
    }
    __syncthreads();
  }
}

// ============ K2: MFMA split-bf16 conv1 + fused conv2 + softmax readout ============
__global__ __launch_bounds__(512, 2) void conv_mfma_kernel(
    const float* __restrict__ ws_xin,
    const unsigned short* __restrict__ A_hi, const unsigned short* __restrict__ A_lo,
    const float* __restrict__ bc1, const float* __restrict__ Wc2,
    const float* __restrict__ bc2, float* __restrict__ out) {
  const int n = blockIdx.x;
  const int tid = threadIdx.x;
  const int w = tid >> 6;     // wave 0..7
  const int l = tid & 63;     // lane
  const int lrow = l & 31;    // A-row / B-col (t) lane index
  const int g = l >> 5;       // k-half

  __shared__ __align__(16) unsigned short bT_hi[128 * KPITCH];  // swizzled [t][kappa]
  __shared__ __align__(16) unsigned short bT_lo[128 * KPITCH];
  __shared__ float plg[3][8][NDD];   // [P,C,M][wave][t] partial logits
  __shared__ float sh_l[NDD];
  __shared__ float sh_e[NDD];
  __shared__ float sh_sc[2];

  for (int i = tid; i < 3 * 8 * NDD; i += 512) ((float*)plg)[i] = 0.0f;

  // build swizzled split-bf16 im2col in LDS: B[kappa][t] = xin[i][t+k-1]
  const float* xn = ws_xin + (size_t)n * (NJJ + NBB) * NDD;
  for (int idx = tid; idx < 112 * 128; idx += 512) {
    int kk = idx >> 7;          // kappa
    int t  = idx & 127;
    float x = 0.0f;
    if (kk < 99) {
      int i3 = kk / 3;
      int k3 = kk - i3 * 3;
      int tt = t + k3 - 1;
      if (tt >= 0 && tt < 128) x = xn[i3 * NDD + tt];
    }
    unsigned int u = __float_as_uint(x);
    unsigned short hi = (unsigned short)(u >> 16);
    float xh = __uint_as_float((u >> 16) << 16);
    unsigned short lo = (unsigned short)(__float_as_uint(x - xh) >> 16);
    int eoff = t * KPITCH + (kk ^ ((t & 15) << 3));   // XOR swizzle (16B granules)
    bT_hi[eoff] = hi;
    bT_lo[eoff] = lo;
  }
  __syncthreads();

#pragma unroll 1
  for (int otile = 0; otile < 4; ++otile) {
    const int o0 = w * 128 + otile * 32;

    short8 Ah[KSTEPS], Al[KSTEPS];
    {
      const unsigned short* arh = A_hi + (size_t)(o0 + lrow) * KPITCH + g * 8;
      const unsigned short* arl = A_lo + (size_t)(o0 + lrow) * KPITCH + g * 8;
#pragma unroll
      for (int ks = 0; ks < KSTEPS; ++ks) {
        Ah[ks] = *(const short8*)(arh + ks * 16);
        Al[ks] = *(const short8*)(arl + ks * 16);
      }
    }
    float w2f[48];
    float bcf[16];
#pragma unroll
    for (int rb = 0; rb < 4; ++rb) {
      int base = o0 + 4 * g + 8 * rb;
      float4 wa = *(const float4*)(Wc2 + base * 3 + 0);
      float4 wb = *(const float4*)(Wc2 + base * 3 + 4);
      float4 wc = *(const float4*)(Wc2 + base * 3 + 8);
      w2f[rb * 12 + 0] = wa.x;  w2f[rb * 12 + 1] = wa.y;  w2f[rb * 12 + 2] = wa.z;
      w2f[rb * 12 + 3] = wa.w;  w2f[rb * 12 + 4] = wb.x;  w2f[rb * 12 + 5] = wb.y;
      w2f[rb * 12 + 6] = wb.z;  w2f[rb * 12 + 7] = wb.w;  w2f[rb * 12 + 8] = wc.x;
      w2f[rb * 12 + 9] = wc.y;  w2f[rb * 12 + 10] = wc.z; w2f[rb * 12 + 11] = wc.w;
      float4 bb = *(const float4*)(bc1 + base);
      bcf[rb * 4 + 0] = bb.x; bcf[rb * 4 + 1] = bb.y;
      bcf[rb * 4 + 2] = bb.z; bcf[rb * 4 + 3] = bb.w;
    }

#pragma unroll 1
    for (int ttile = 0; ttile < 4; ++ttile) {
      const int trow = ttile * 32 + lrow;
      float16 acc;
#pragma unroll
      for (int r = 0; r < 16; ++r) acc[r] = 0.0f;

      const unsigned short* brh = bT_hi + trow * KPITCH;
      const unsigned short* brl = bT_lo + trow * KPITCH;
      const int sw = (trow & 15) << 3;
#pragma unroll
      for (int ks = 0; ks < KSTEPS; ++ks) {
        int eoff = (ks * 16 + g * 8) ^ sw;
        short8 bh = *(const short8*)(brh + eoff);
        short8 bl = *(const short8*)(brl + eoff);
        acc = __builtin_amdgcn_mfma_f32_32x32x16_bf16(Ah[ks], bh, acc, 0, 0, 0);
        acc = __builtin_amdgcn_mfma_f32_32x32x16_bf16(Al[ks], bh, acc, 0, 0, 0);
        acc = __builtin_amdgcn_mfma_f32_32x32x16_bf16(Ah[ks], bl, acc, 0, 0, 0);
      }

      float sP = 0.0f, sC = 0.0f, sM = 0.0f;
#pragma unroll
      for (int r = 0; r < 16; ++r) {
        float h = fmaxf(acc[r] + bcf[(r >> 2) * 4 + (r & 3)], 0.0f);
        sP = fmaf(h, w2f[(r >> 2) * 12 + (r & 3) * 3 + 0], sP);
        sC = fmaf(h, w2f[(r >> 2) * 12 + (r & 3) * 3 + 1], sC);
        sM = fmaf(h, w2f[(r >> 2) * 12 + (r & 3) * 3 + 2], sM);
      }
      sP += __shfl_xor(sP, 32, 64);
      sC += __shfl_xor(sC, 32, 64);
      sM += __shfl_xor(sM, 32, 64);
      if (l < 32) {
        plg[0][w][trow] += sP;
        plg[1][w][trow] += sC;
        plg[2][w][trow] += sM;
      }
    }
  }
  __syncthreads();

  if (tid < NDD) {
    int t = tid;
    float lg = bc2[0];
#pragma unroll
    for (int ww = 0; ww < 8; ++ww) lg += plg[1][ww][t];
    if (t > 0) {
#pragma unroll
      for (int ww = 0; ww < 8; ++ww) lg += plg[0][ww][t - 1];
    }
    if (t < NDD - 1) {
#pragma unroll
      for (int ww = 0; ww < 8; ++ww) lg += plg[2][ww][t + 1];
    }
    sh_l[t] = lg;
  }
  __syncthreads();
  if (tid < 64) {
    float v1 = sh_l[tid], v2 = sh_l[tid + 64];
    float mv; int mi;
    if (v2 > v1) { mv = v2; mi = tid + 64; } else { mv = v1; mi = tid; }
#pragma unroll
    for (int off = 32; off >= 1; off >>= 1) {
      float ov = __shfl_xor(mv, off, 64);
      int   oi = __shfl_xor(mi, off, 64);
      if (ov > mv || (ov == mv && oi < mi)) { mv = ov; mi = oi; }
    }
    if (tid == 0) { sh_sc[0] = mv; ((int*)sh_sc)[1] = mi; }
  }
  __syncthreads();
  const float gmax = sh_sc[0];
  const int gidx = ((const int*)sh_sc)[1];
  if (tid < NDD) sh_e[tid] = expf(sh_l[tid] - gmax);
  __syncthreads();
  if (tid < 64) {
    float S = warp_red_sum(sh_e[tid] + sh_e[tid + 64]);
    float a1 = 0.0f, a2 = 0.0f;
#pragma unroll
    for (int k = 0; k < 2; ++k) {
      int t = tid + k * 64;
      float vol = sh_e[t] / S;
      float msk = (fabsf((float)t - (float)gidx) <= 5.0f) ? 1.0f : 0.0f;
      float mvv = vol * msk;
      a1 += mvv;
      a2 += mvv * (float)t;
    }
    a1 = warp_red_sum(a1);
    a2 = warp_red_sum(a2);
    if (tid == 0) {
      float pred = a2 / (a1 + 1e-8f);
      out[n] = pred / 127.0f * 6000.0f + 2000.0f;
    }
  }
}

extern "C" void kernel_launch(void* const* d_in, const int* in_sizes, int n_in,
                              void* d_out, int out_size, void* d_ws, size_t ws_size,
                              hipStream_t stream) {
  (void)in_sizes; (void)n_in; (void)out_size; (void)ws_size;
  const float* kpts        = (const float*)d_in[0];
  const float* joint_vis   = (const float*)d_in[2];
  const float* cam_R       = (const float*)d_in[5];
  const float* cam_T       = (const float*)d_in[6];
  const float* cam_f       = (const float*)d_in[7];
  const float* cam_c       = (const float*)d_in[8];
  const float* image_wh    = (const float*)d_in[9];
  const int*   num_persons = (const int*)d_in[10];
  const float* Wr1 = (const float*)d_in[11];
  const float* br1 = (const float*)d_in[12];
  const float* Wr2 = (const float*)d_in[13];
  const float* br2 = (const float*)d_in[14];
  const float* Wc1 = (const float*)d_in[15];
  const float* bc1 = (const float*)d_in[16];
  const float* Wc2 = (const float*)d_in[17];
  const float* bc2 = (const float*)d_in[18];
  float* out = (float*)d_out;

  unsigned short* A_hi = (unsigned short*)d_ws;              // 1024*128 u16
  unsigned short* A_lo = A_hi + HID * KPITCH;                // 1024*128 u16
  float* ws_xin = (float*)(A_lo + HID * KPITCH);             // 640*33*128 f32

  hipLaunchKernelGGL(prep_kernel, dim3((HID * KPITCH) / 256), dim3(256), 0, stream,
                     Wc1, A_hi, A_lo);
  hipLaunchKernelGGL(pose_front_kernel, dim3(BB * NPP), dim3(512), 0, stream,
                     kpts, joint_vis, cam_R, cam_T, cam_f, cam_c, image_wh,
                     num_persons, Wr1, br1, Wr2, br2, ws_xin);
  hipLaunchKernelGGL(conv_mfma_kernel, dim3(BB * NPP), dim3(512), 0, stream,
                     ws_xin, A_hi, A_lo, bc1, Wc2, bc2, out);
}

// Round 5
// 190.253 us; speedup vs baseline: 4.2509x; 1.0147x over previous
//
#include <hip/hip_runtime.h>
#include <math.h>

#define VV  5
#define BB  32
#define NPP 20
#define NJJ 17
#define NBB 16
#define NDD 128
#define HID 1024
#define KPITCH 128          // padded kappa pitch (elements)
#define KSTEPS 7            // 7 * 16 = 112 >= 99
#define PRP 36              // padded pr row (34 used, 144B = 16B aligned)
#define VRP 20              // padded vr row (17 used, 80B = 16B aligned)

typedef __attribute__((ext_vector_type(8))) short short8;
typedef __attribute__((ext_vector_type(16))) float float16;

static constexpr int BONE_A[NBB] = {0,0,1,2,5,5,7,6,8,5,6,11,11,13,12,14};
static constexpr int BONE_B[NBB] = {1,2,3,4,6,7,9,8,10,11,12,12,13,15,14,16};

__device__ __forceinline__ float warp_red_sum(float v) {
#pragma unroll
  for (int off = 32; off >= 1; off >>= 1) v += __shfl_xor(v, off, 64);
  return v;
}

// ============ K0: split Wc1 into bf16 hi/lo, kappa-padded [1024][128] ============
__global__ __launch_bounds__(256) void prep_kernel(
    const float* __restrict__ Wc1, unsigned short* __restrict__ A_hi,
    unsigned short* __restrict__ A_lo) {
  int idx = blockIdx.x * 256 + threadIdx.x;    // over 1024*128
  int o = idx >> 7, kk = idx & 127;
  float x = (kk < 99) ? Wc1[o * 99 + kk] : 0.0f;
  unsigned int u = __float_as_uint(x);
  unsigned short hi = (unsigned short)(u >> 16);
  float xh = __uint_as_float((u >> 16) << 16);
  float r = x - xh;
  unsigned short lo = (unsigned short)(__float_as_uint(r) >> 16);
  A_hi[idx] = hi;
  A_lo[idx] = lo;
}

// ===================== K1: geometry + matching -> xin =====================
// 512 threads: thread = (rvv = tid>>7 in 0..3 -> ref view rvv+1, d = tid&127).
__global__ __launch_bounds__(512, 8) void pose_front_kernel(
    const float* __restrict__ kpts, const float* __restrict__ joint_vis,
    const float* __restrict__ cam_R, const float* __restrict__ cam_T,
    const float* __restrict__ cam_f, const float* __restrict__ cam_c,
    const float* __restrict__ image_wh, const int* __restrict__ num_persons,
    const float* __restrict__ Wr1, const float* __restrict__ br1,
    const float* __restrict__ Wr2, const float* __restrict__ br2,
    float* __restrict__ ws_xin) {
  const int n = blockIdx.x;
  const int b = n / NPP;
  const int p = n % NPP;
  const int tid = threadIdx.x;
  const int wv = tid >> 6, ln = tid & 63;
  const int rvv = tid >> 7;          // 0..3 -> view rvv+1
  const int d   = tid & (NDD - 1);   // depth bin

  __shared__ float sh_x[NJJ * 2];
  __shared__ float sh_h[HID];
  __shared__ float sh_rough[NJJ];
  __shared__ float sh_base[NJJ][3];
  __shared__ __align__(16) float sh_pr[4][NPP][PRP];
  __shared__ __align__(16) float sh_vr[4][NPP][VRP];
  __shared__ float sh_stage[4][8][NDD];
  __shared__ float sh_s2red[NBB][NDD];

  // Phase 1a: normalized view-0 keypoints
  if (tid < NJJ * 2) {
    int j = tid >> 1, c = tid & 1;
    float k = kpts[((size_t)(b * NPP + p)) * NJJ * 2 + j * 2 + c];
    sh_x[tid] = k / image_wh[c];
  }
  __syncthreads();

  // Phase 1b: h = relu(x @ Wr1.T + br1), 2 rows/thread
#pragma unroll
  for (int k = 0; k < 2; ++k) {
    int m = tid + k * 512;
    float acc = br1[m];
#pragma unroll
    for (int c = 0; c < NJJ * 2; ++c) acc = fmaf(Wr1[m * (NJJ * 2) + c], sh_x[c], acc);
    sh_h[m] = fmaxf(acc, 0.0f);
  }
  __syncthreads();

  // Phase 1c: rough depths, 17 joints over 8 waves
  for (int j = wv; j < NJJ; j += 8) {
    float part = 0.0f;
    for (int m = ln; m < HID; m += 64) part = fmaf(Wr2[j * HID + m], sh_h[m], part);
    part = warp_red_sum(part);
    if (ln == 0) sh_rough[j] = (part + br2[j]) * 1000.0f;
  }
  // Phase 2: ray bases
  if (tid < NJJ) {
    int j = tid;
    const float* R0 = cam_R + (size_t)b * 9;
    float c0x = cam_c[b * 2 + 0], c0y = cam_c[b * 2 + 1];
    float f0x = cam_f[b * 2 + 0], f0y = cam_f[b * 2 + 1];
    float kx = kpts[((size_t)(b * NPP + p)) * NJJ * 2 + j * 2 + 0];
    float ky = kpts[((size_t)(b * NPP + p)) * NJJ * 2 + j * 2 + 1];
    float ux = (kx - c0x) / f0x;
    float uy = (ky - c0y) / f0y;
#pragma unroll
    for (int i = 0; i < 3; ++i)
      sh_base[j][i] = R0[0 * 3 + i] * ux + R0[1 * 3 + i] * uy + R0[2 * 3 + i];
  }
  // Stage all 4 ref views' keypoints + visibility (padded rows, pads zeroed)
#pragma unroll
  for (int rr = 0; rr < 4; ++rr) {
    const float* prg = kpts + ((size_t)(rr + 1) * BB + b) * NPP * NJJ * 2;
    for (int idx = tid; idx < NPP * NJJ * 2; idx += 512)
      sh_pr[rr][idx / 34][idx % 34] = prg[idx];
    const float* vrg = joint_vis + ((size_t)(rr + 1) * BB + b) * NPP * NJJ;
    for (int idx = tid; idx < NPP * NJJ; idx += 512)
      sh_vr[rr][idx / 17][idx % 17] = vrg[idx];
  }
  if (tid < 4 * NPP) {
    int rr = tid >> 5, q = tid & 31;
    if (q < NPP) {
      sh_pr[rr][q][34] = 0.0f; sh_pr[rr][q][35] = 0.0f;
      sh_vr[rr][q][17] = 0.0f; sh_vr[rr][q][18] = 0.0f; sh_vr[rr][q][19] = 0.0f;
    }
  }
  __syncthreads();

  // Phase 3: one (view, depth) per thread
  float partA[NJJ];     // sc*bd
  float partS[NBB];     // scb*v0
  unsigned int maskB;   // bd bits (bd in {0,1} exactly: vis * inbound)
  float partb2;         // v0
  {
    const int rv = rvv + 1;
    const int vb = rv * BB + b;
    const float* Rr = cam_R + (size_t)vb * 9;
    const float R00 = Rr[0], R01 = Rr[1], R02 = Rr[2];
    const float R10 = Rr[3], R11 = Rr[4], R12 = Rr[5];
    const float R20 = Rr[6], R21 = Rr[7], R22 = Rr[8];
    const float Trx = cam_T[vb * 3 + 0], Try = cam_T[vb * 3 + 1], Trz = cam_T[vb * 3 + 2];
    const float frx = cam_f[vb * 2 + 0], fry = cam_f[vb * 2 + 1];
    const float crx = cam_c[vb * 2 + 0], cry = cam_c[vb * 2 + 1];
    const float wmax = image_wh[vb * 2 + 0] - 1.0f;
    const float hmax = image_wh[vb * 2 + 1] - 1.0f;
    const int nprv = num_persons[vb];
    const float T0x = cam_T[b * 3 + 0], T0y = cam_T[b * 3 + 1], T0z = cam_T[b * 3 + 2];
    const float lab = ((float)d / 127.0f) * 6000.0f + 2000.0f;

    float px[NJJ], py[NJJ];
#pragma unroll
    for (int j = 0; j < NJJ; ++j) {
      float dep = lab + sh_rough[j];
      float p0 = fmaf(dep, sh_base[j][0], T0x);
      float p1 = fmaf(dep, sh_base[j][1], T0y);
      float p2 = fmaf(dep, sh_base[j][2], T0z);
      float q0 = p0 - Trx, q1 = p1 - Try, q2 = p2 - Trz;
      float xc0 = R00 * q0 + R01 * q1 + R02 * q2;
      float xc1 = R10 * q0 + R11 * q1 + R12 * q2;
      float xc2 = R20 * q0 + R21 * q1 + R22 * q2 + 1e-8f;
      px[j] = xc0 / xc2 * frx + crx;
      py[j] = xc1 / xc2 * fry + cry;
    }

    // argmin over candidates, float4 LDS reads, exact j-ascending chains
    float best = 3.4e38f;
    int mm = 0;
#pragma unroll 1
    for (int q = 0; q < NPP; ++q) {
      const float4* pr4 = (const float4*)(&sh_pr[rvv][q][0]);
      const float4* vr4 = (const float4*)(&sh_vr[rvv][q][0]);
      float num = 0.0f, den = 0.0f;
#pragma unroll
      for (int g4 = 0; g4 < 4; ++g4) {
        float4 w  = vr4[g4];
        float4 pa = pr4[2 * g4 + 0];
        float4 pb = pr4[2 * g4 + 1];
        { float dx = px[4*g4+0] - pa.x, dy = py[4*g4+0] - pa.y; num = fmaf(w.x, dx*dx + dy*dy, num); den += w.x; }
        { float dx = px[4*g4+1] - pa.z, dy = py[4*g4+1] - pa.w; num = fmaf(w.y, dx*dx + dy*dy, num); den += w.y; }
        { float dx = px[4*g4+2] - pb.x, dy = py[4*g4+2] - pb.y; num = fmaf(w.z, dx*dx + dy*dy, num); den += w.z; }
        { float dx = px[4*g4+3] - pb.z, dy = py[4*g4+3] - pb.w; num = fmaf(w.w, dx*dx + dy*dy, num); den += w.w; }
      }
      {
        float w16 = sh_vr[rvv][q][16];
        float4 pc = pr4[8];
        float dx = px[16] - pc.x, dy = py[16] - pc.y;
        num = fmaf(w16, dx*dx + dy*dy, num); den += w16;
      }
      float pd = num / (den + 1e-8f);
      if (q >= nprv) pd = 100000.0f;
      if (pd < best) { best = pd; mm = q; }
    }

    // joint scores vs matched person mm (per-lane divergent LDS reads)
    maskB = 0u;
#pragma unroll
    for (int j = 0; j < NJJ; ++j) {
      float mx = sh_pr[rvv][mm][j * 2 + 0];
      float my = sh_pr[rvv][mm][j * 2 + 1];
      float mv = sh_vr[rvv][mm][j];
      float dx = px[j] - mx, dy = py[j] - my;
      float sc = expf(-sqrtf(dx * dx + dy * dy + 1e-12f) / 100.0f);
      float inb = (px[j] >= 0.0f && py[j] >= 0.0f && px[j] <= wmax && py[j] <= hmax) ? 1.0f : 0.0f;
      float bd = inb * mv;                 // exactly 0.0 or 1.0
      partA[j] = sc * bd;
      maskB |= ((unsigned int)(bd != 0.0f)) << j;
    }
    float v0 = sh_vr[rvv][mm][0];
#pragma unroll
    for (int nb = 0; nb < NBB; ++nb) {
      const int a = BONE_A[nb], c = BONE_B[nb];
      float ax = sh_pr[rvv][mm][a * 2 + 0], ay = sh_pr[rvv][mm][a * 2 + 1];
      float cx = sh_pr[rvv][mm][c * 2 + 0], cy = sh_pr[rvv][mm][c * 2 + 1];
      float dmx = ax - cx, dmy = ay - cy;
      float blm = sqrtf(dmx * dmx + dmy * dmy + 1e-12f);
      float dpx = px[a] - px[c], dpy = py[a] - py[c];
      float blp = sqrtf(dpx * dpx + dpy * dpy + 1e-12f);
      float scb = expf(-fabsf(blm - blp) / 5.0f);
      partS[nb] = scb * v0;
    }
    partb2 = v0;
  }

  // Phase 4: deterministic cross-view reduction in rounds of 8 channels.
  // ch layout: 0..33 = (sj0,bj0,...,sj16,bj16); 34..49 = s2[0..15]; 50 = b2.
  float* xo = ws_xin + (size_t)n * (NJJ + NBB) * NDD;
#pragma unroll
  for (int r = 0; r < 7; ++r) {
#pragma unroll
    for (int i = 0; i < 8; ++i) {
      const int ch = r * 8 + i;
      if (ch <= 50) {
        float v;
        if (ch < 34) v = (ch & 1) ? (float)((maskB >> (ch >> 1)) & 1u) : partA[ch >> 1];
        else if (ch < 50) v = partS[ch - 34];
        else v = partb2;
        sh_stage[rvv][i][d] = v;
      }
    }
    __syncthreads();
    if (tid < NDD) {
      float sjv = 0.0f;
#pragma unroll
      for (int i = 0; i < 8; ++i) {
        const int ch = r * 8 + i;
        if (ch > 50) continue;
        float s = ((sh_stage[0][i][tid] + sh_stage[1][i][tid]) + sh_stage[2][i][tid]) + sh_stage[3][i][tid];
        if (ch < 34) {
          if ((ch & 1) == 0) sjv = s;
          else xo[(ch >> 1) * NDD + tid] = sjv / (s + 1e-8f);
        } else if (ch < 50) {
          sh_s2red[ch - 34][tid] = s;
        } else {
          float den2 = s + 1e-8f;
#pragma unroll
          for (int nb = 0; nb < NBB; ++nb)
            xo[(NJJ + nb) * NDD + tid] = sh_s2red[nb][tid] / den2;
        }
      }
    }
    __syncthreads();
  }
}

// ============ K2: MFMA split-bf16 conv1 + fused conv2 + softmax readout ============
__global__ __launch_bounds__(512, 2) void conv_mfma_kernel(
    const float* __restrict__ ws_xin,
    const unsigned short* __restrict__ A_hi, const unsigned short* __restrict__ A_lo,
    const float* __restrict__ bc1, const float* __restrict__ Wc2,
    const float* __restrict__ bc2, float* __restrict__ out) {
  const int n = blockIdx.x;
  const int tid = threadIdx.x;
  const int w = tid >> 6;     // wave 0..7
  const int l = tid & 63;     // lane
  const int lrow = l & 31;    // A-row / B-col (t) lane index
  const int g = l >> 5;       // k-half

  __shared__ __align__(16) unsigned short bT_hi[128 * KPITCH];  // swizzled [t][kappa]
  __shared__ __align__(16) unsigned short bT_lo[128 * KPITCH];
  __shared__ float plg[3][8][NDD];   // [P,C,M][wave][t] partial logits
  __shared__ float sh_l[NDD];
  __shared__ float sh_e[NDD];
  __shared__ float sh_sc[2];

  for (int i = tid; i < 3 * 8 * NDD; i += 512) ((float*)plg)[i] = 0.0f;

  // build swizzled split-bf16 im2col in LDS: B[kappa][t] = xin[i][t+k-1]
  const float* xn = ws_xin + (size_t)n * (NJJ + NBB) * NDD;
  for (int idx = tid; idx < 112 * 128; idx += 512) {
    int kk = idx >> 7;          // kappa
    int t  = idx & 127;
    float x = 0.0f;
    if (kk < 99) {
      int i3 = kk / 3;
      int k3 = kk - i3 * 3;
      int tt = t + k3 - 1;
      if (tt >= 0 && tt < 128) x = xn[i3 * NDD + tt];
    }
    unsigned int u = __float_as_uint(x);
    unsigned short hi = (unsigned short)(u >> 16);
    float xh = __uint_as_float((u >> 16) << 16);
    unsigned short lo = (unsigned short)(__float_as_uint(x - xh) >> 16);
    int eoff = t * KPITCH + (kk ^ ((t & 15) << 3));   // XOR swizzle (16B granules)
    bT_hi[eoff] = hi;
    bT_lo[eoff] = lo;
  }
  __syncthreads();

#pragma unroll 1
  for (int otile = 0; otile < 4; ++otile) {
    const int o0 = w * 128 + otile * 32;

    short8 Ah[KSTEPS], Al[KSTEPS];
    {
      const unsigned short* arh = A_hi + (size_t)(o0 + lrow) * KPITCH + g * 8;
      const unsigned short* arl = A_lo + (size_t)(o0 + lrow) * KPITCH + g * 8;
#pragma unroll
      for (int ks = 0; ks < KSTEPS; ++ks) {
        Ah[ks] = *(const short8*)(arh + ks * 16);
        Al[ks] = *(const short8*)(arl + ks * 16);
      }
    }
    float w2f[48];
    float bcf[16];
#pragma unroll
    for (int rb = 0; rb < 4; ++rb) {
      int base = o0 + 4 * g + 8 * rb;
      float4 wa = *(const float4*)(Wc2 + base * 3 + 0);
      float4 wb = *(const float4*)(Wc2 + base * 3 + 4);
      float4 wc = *(const float4*)(Wc2 + base * 3 + 8);
      w2f[rb * 12 + 0] = wa.x;  w2f[rb * 12 + 1] = wa.y;  w2f[rb * 12 + 2] = wa.z;
      w2f[rb * 12 + 3] = wa.w;  w2f[rb * 12 + 4] = wb.x;  w2f[rb * 12 + 5] = wb.y;
      w2f[rb * 12 + 6] = wb.z;  w2f[rb * 12 + 7] = wb.w;  w2f[rb * 12 + 8] = wc.x;
      w2f[rb * 12 + 9] = wc.y;  w2f[rb * 12 + 10] = wc.z; w2f[rb * 12 + 11] = wc.w;
      float4 bb = *(const float4*)(bc1 + base);
      bcf[rb * 4 + 0] = bb.x; bcf[rb * 4 + 1] = bb.y;
      bcf[rb * 4 + 2] = bb.z; bcf[rb * 4 + 3] = bb.w;
    }

#pragma unroll 1
    for (int ttile = 0; ttile < 4; ++ttile) {
      const int trow = ttile * 32 + lrow;
      float16 acc;
#pragma unroll
      for (int r = 0; r < 16; ++r) acc[r] = 0.0f;

      const unsigned short* brh = bT_hi + trow * KPITCH;
      const unsigned short* brl = bT_lo + trow * KPITCH;
      const int sw = (trow & 15) << 3;
#pragma unroll
      for (int ks = 0; ks < KSTEPS; ++ks) {
        int eoff = (ks * 16 + g * 8) ^ sw;
        short8 bh = *(const short8*)(brh + eoff);
        short8 bl = *(const short8*)(brl + eoff);
        acc = __builtin_amdgcn_mfma_f32_32x32x16_bf16(Ah[ks], bh, acc, 0, 0, 0);
        acc = __builtin_amdgcn_mfma_f32_32x32x16_bf16(Al[ks], bh, acc, 0, 0, 0);
        acc = __builtin_amdgcn_mfma_f32_32x32x16_bf16(Ah[ks], bl, acc, 0, 0, 0);
      }

      float sP = 0.0f, sC = 0.0f, sM = 0.0f;
#pragma unroll
      for (int r = 0; r < 16; ++r) {
        float h = fmaxf(acc[r] + bcf[(r >> 2) * 4 + (r & 3)], 0.0f);
        sP = fmaf(h, w2f[(r >> 2) * 12 + (r & 3) * 3 + 0], sP);
        sC = fmaf(h, w2f[(r >> 2) * 12 + (r & 3) * 3 + 1], sC);
        sM = fmaf(h, w2f[(r >> 2) * 12 + (r & 3) * 3 + 2], sM);
      }
      sP += __shfl_xor(sP, 32, 64);
      sC += __shfl_xor(sC, 32, 64);
      sM += __shfl_xor(sM, 32, 64);
      if (l < 32) {
        plg[0][w][trow] += sP;
        plg[1][w][trow] += sC;
        plg[2][w][trow] += sM;
      }
    }
  }
  __syncthreads();

  if (tid < NDD) {
    int t = tid;
    float lg = bc2[0];
#pragma unroll
    for (int ww = 0; ww < 8; ++ww) lg += plg[1][ww][t];
    if (t > 0) {
#pragma unroll
      for (int ww = 0; ww < 8; ++ww) lg += plg[0][ww][t - 1];
    }
    if (t < NDD - 1) {
#pragma unroll
      for (int ww = 0; ww < 8; ++ww) lg += plg[2][ww][t + 1];
    }
    sh_l[t] = lg;
  }
  __syncthreads();
  if (tid < 64) {
    float v1 = sh_l[tid], v2 = sh_l[tid + 64];
    float mv; int mi;
    if (v2 > v1) { mv = v2; mi = tid + 64; } else { mv = v1; mi = tid; }
#pragma unroll
    for (int off = 32; off >= 1; off >>= 1) {
      float ov = __shfl_xor(mv, off, 64);
      int   oi = __shfl_xor(mi, off, 64);
      if (ov > mv || (ov == mv && oi < mi)) { mv = ov; mi = oi; }
    }
    if (tid == 0) { sh_sc[0] = mv; ((int*)sh_sc)[1] = mi; }
  }
  __syncthreads();
  const float gmax = sh_sc[0];
  const int gidx = ((const int*)sh_sc)[1];
  if (tid < NDD) sh_e[tid] = expf(sh_l[tid] - gmax);
  __syncthreads();
  if (tid < 64) {
    float S = warp_red_sum(sh_e[tid] + sh_e[tid + 64]);
    float a1 = 0.0f, a2 = 0.0f;
#pragma unroll
    for (int k = 0; k < 2; ++k) {
      int t = tid + k * 64;
      float vol = sh_e[t] / S;
      float msk = (fabsf((float)t - (float)gidx) <= 5.0f) ? 1.0f : 0.0f;
      float mvv = vol * msk;
      a1 += mvv;
      a2 += mvv * (float)t;
    }
    a1 = warp_red_sum(a1);
    a2 = warp_red_sum(a2);
    if (tid == 0) {
      float pred = a2 / (a1 + 1e-8f);
      out[n] = pred / 127.0f * 6000.0f + 2000.0f;
    }
  }
}

extern "C" void kernel_launch(void* const* d_in, const int* in_sizes, int n_in,
                              void* d_out, int out_size, void* d_ws, size_t ws_size,
                              hipStream_t stream) {
  (void)in_sizes; (void)n_in; (void)out_size; (void)ws_size;
  const float* kpts        = (const float*)d_in[0];
  const float* joint_vis   = (const float*)d_in[2];
  const float* cam_R       = (const float*)d_in[5];
  const float* cam_T       = (const float*)d_in[6];
  const float* cam_f       = (const float*)d_in[7];
  const float* cam_c       = (const float*)d_in[8];
  const float* image_wh    = (const float*)d_in[9];
  const int*   num_persons = (const int*)d_in[10];
  const float* Wr1 = (const float*)d_in[11];
  const float* br1 = (const float*)d_in[12];
  const float* Wr2 = (const float*)d_in[13];
  const float* br2 = (const float*)d_in[14];
  const float* Wc1 = (const float*)d_in[15];
  const float* bc1 = (const float*)d_in[16];
  const float* Wc2 = (const float*)d_in[17];
  const float* bc2 = (const float*)d_in[18];
  float* out = (float*)d_out;

  unsigned short* A_hi = (unsigned short*)d_ws;              // 1024*128 u16
  unsigned short* A_lo = A_hi + HID * KPITCH;                // 1024*128 u16
  float* ws_xin = (float*)(A_lo + HID * KPITCH);             // 640*33*128 f32

  hipLaunchKernelGGL(prep_kernel, dim3((HID * KPITCH) / 256), dim3(256), 0, stream,
                     Wc1, A_hi, A_lo);
  hipLaunchKernelGGL(pose_front_kernel, dim3(BB * NPP), dim3(512), 0, stream,
                     kpts, joint_vis, cam_R, cam_T, cam_f, cam_c, image_wh,
                     num_persons, Wr1, br1, Wr2, br2, ws_xin);
  hipLaunchKernelGGL(conv_mfma_kernel, dim3(BB * NPP), dim3(512), 0, stream,
                     ws_xin, A_hi, A_lo, bc1, Wc2, bc2, out);
}